// Round 11
// baseline (3589.868 us; speedup 1.0000x reference)
//
#include <hip/hip_runtime.h>
#include <math.h>

#define AGENTS 128
#define DIM 256
#define MEM_LEN 1024
#define PRED 12
#define MAXS (PRED * AGENTS)   // 1536
#define NWG 16

typedef __attribute__((ext_vector_type(8))) short short8;
typedef __attribute__((ext_vector_type(4))) float f32x4;

#define MFMA(a, b, c) __builtin_amdgcn_mfma_f32_16x16x32_bf16(a, b, c, 0, 0, 0)

__device__ __forceinline__ unsigned short f2bf(float f) {
  union { float f; unsigned u; } v; v.f = f;
  unsigned r = v.u + 0x7fffu + ((v.u >> 16) & 1u);   // RNE
  return (unsigned short)(r >> 16);
}
__device__ __forceinline__ float bfval(unsigned short b) {
  union { unsigned u; float f; } v; v.u = (unsigned)b << 16; return v.f;
}
__device__ __forceinline__ short8 afrag8(const float* p) {
  float4 a = *(const float4*)p;
  float4 b = *(const float4*)(p + 4);
  short8 r;
  r[0] = (short)f2bf(a.x); r[1] = (short)f2bf(a.y);
  r[2] = (short)f2bf(a.z); r[3] = (short)f2bf(a.w);
  r[4] = (short)f2bf(b.x); r[5] = (short)f2bf(b.y);
  r[6] = (short)f2bf(b.z); r[7] = (short)f2bf(b.w);
  return r;
}

// relaxed agent-scope store: sc1 write-through to coherence point, NO wbl2/inv
template <typename T>
__device__ __forceinline__ void ast(T* p, T v) {
  __hip_atomic_store(p, v, __ATOMIC_RELAXED, __HIP_MEMORY_SCOPE_AGENT);
}

// LN stats from 4 col-block partials pst[row][cb]=(sum,sumsq)
__device__ __forceinline__ void ln_stats(const float* __restrict__ pst, int row,
                                         float& mean, float& rstd) {
  float4 p0 = *(const float4*)(pst + row * 8);
  float4 p1 = *(const float4*)(pst + row * 8 + 4);
  float s  = p0.x + p0.z + p1.x + p1.z;
  float ss = p0.y + p0.w + p1.y + p1.w;
  mean = s * (1.0f / 256.0f);
  rstd = rsqrtf(ss * (1.0f / 256.0f) - mean * mean + 1e-5f);
}

__device__ __forceinline__ short8 afragLN(const float* __restrict__ yr,
                                          const float* __restrict__ lg,
                                          const float* __restrict__ lb,
                                          int k, float mean, float rstd) {
  float4 a = *(const float4*)(yr + k), b = *(const float4*)(yr + k + 4);
  float4 ga = *(const float4*)(lg + k), gb = *(const float4*)(lg + k + 4);
  float4 ba = *(const float4*)(lb + k), bb = *(const float4*)(lb + k + 4);
  short8 r;
  r[0] = (short)f2bf((a.x - mean) * rstd * ga.x + ba.x);
  r[1] = (short)f2bf((a.y - mean) * rstd * ga.y + ba.y);
  r[2] = (short)f2bf((a.z - mean) * rstd * ga.z + ba.z);
  r[3] = (short)f2bf((a.w - mean) * rstd * ga.w + ba.w);
  r[4] = (short)f2bf((b.x - mean) * rstd * gb.x + bb.x);
  r[5] = (short)f2bf((b.y - mean) * rstd * gb.y + bb.y);
  r[6] = (short)f2bf((b.z - mean) * rstd * gb.z + bb.z);
  r[7] = (short)f2bf((b.w - mean) * rstd * gb.w + bb.w);
  return r;
}

// ---------------------------------------------------------------------------
struct MegaP {
  const float *last_pos, *ds, *mask;
  const float *in_b, *out_W, *out_b;
  const float *sa_bq, *sa_bk, *sa_bv, *sa_bo;
  const float *ca_bq, *ca_bo;
  const float *ff_b1, *ff_b2;
  const float *ln1_g, *ln1_b, *ln2_g, *ln2_b, *ln3_g, *ln3_b;
  float *out;
  const float *peA, *peT;
  float *x0rot;                        // 12 x [128][256] fp32
  unsigned short *xb0rot;              // 12 x [128][256] bf16
  unsigned short *qrot, *abufrot, *cabufrot;  // 24 x 32768 bf16 each
  float *Y1rot, *Y2rot, *Y3rot;        // 24 x 32768 fp32 each
  float *pst1rot, *pst2rot, *pst3rot;  // 24 x 1024 fp32 each
  unsigned short *midrot;              // 24 x [128][1024] bf16
  unsigned short *saK, *saV;           // per layer: K [8][1536][32], V blocked [96][256][16]
  const unsigned short *memK, *memV;   // per layer: K [8][1024][32], V blocked [64][256][16]
  const unsigned short *dxdb, *ffW1b, *ffW2b, *inWb;
  unsigned *barCnt;
};

// Fully-relaxed monotonic grid barrier. Safe because all cross-WG data is
// written with sc1 write-through stores and hipcc drains vmcnt(0) before
// s_barrier, so data is at the coherence point before the counter RMW issues.
// No buffer_wbl2, no buffer_inv anywhere in the loop.
__device__ __forceinline__ void gridbar(unsigned* cnt, unsigned& tgt) {
  __syncthreads();
  tgt += NWG;
  if (threadIdx.x == 0) {
    unsigned old = __hip_atomic_fetch_add(cnt, 1u, __ATOMIC_RELAXED,
                                          __HIP_MEMORY_SCOPE_AGENT);
    if (old + 1u < tgt) {
      while (__hip_atomic_load(cnt, __ATOMIC_RELAXED,
                               __HIP_MEMORY_SCOPE_AGENT) < tgt)
        __builtin_amdgcn_s_sleep(1);
    }
  }
  __syncthreads();
  asm volatile("" ::: "memory");
}

// one 16-key score tile: MFMA -> exp -> bf16 pack + lsum
__device__ __forceinline__ void score_tile(short8 kf, short8 qf, const float* m4,
                                           unsigned short* dst, float& lsum) {
  const float scale = 0.17677669529663687f;
  f32x4 zz = {};
  f32x4 sc = MFMA(kf, qf, zz);
  unsigned short b0 = f2bf(__expf(sc[0] * scale + m4[0]));
  unsigned short b1 = f2bf(__expf(sc[1] * scale + m4[1]));
  unsigned short b2 = f2bf(__expf(sc[2] * scale + m4[2]));
  unsigned short b3 = f2bf(__expf(sc[3] * scale + m4[3]));
  lsum += bfval(b0) + bfval(b1) + bfval(b2) + bfval(b3);
  uint2 u2;
  u2.x = (unsigned)b0 | ((unsigned)b1 << 16);
  u2.y = (unsigned)b2 | ((unsigned)b3 << 16);
  *(uint2*)dst = u2;
}

// flash attention over S keys, one head, 16 queries per wave; V blocked.
__device__ __forceinline__ void flash64(const unsigned short* __restrict__ kh,
                                        const unsigned short* __restrict__ vbase,
                                        int hcol, short8 qf, const float mk[2][4][4],
                                        int S, unsigned short* psrow,
                                        int c15, int g8, int g,
                                        float& lsum, f32x4& oa0, f32x4& oa1) {
  for (int kc = 0; kc < S; kc += 64) {
    const int pp = (kc >> 6) & 1;
#pragma unroll
    for (int t = 0; t < 4; ++t) {
      short8 kf = *(const short8*)(kh + (kc + t * 16 + c15) * 32 + g8);
      score_tile(kf, qf, mk[pp][t], psrow + t * 16 + g * 4, lsum);
    }
#pragma unroll
    for (int ks = 0; ks < 2; ++ks) {
      short8 pf = *(const short8*)(psrow + ks * 32 + g8);
      int j = kc + ks * 32 + g8;
      const unsigned short* vb = vbase + (j >> 4) * 4096 + (j & 15);
      short8 v0 = *(const short8*)(vb + (hcol + c15) * 16);
      short8 v1 = *(const short8*)(vb + (hcol + c15 + 16) * 16);
      oa0 = MFMA(v0, pf, oa0);
      oa1 = MFMA(v1, pf, oa1);
    }
  }
}

// ---------------------------------------------------------------------------
// Phase: prev-step out-proj (row-local redundant) + embed GEMM. WGs 0..7.
// s==PRED: out-proj only.
// ---------------------------------------------------------------------------
__device__ void ph_embed(const MegaP& p, int wg, int s, float (*sscene)[2]) {
  if (wg >= 8) return;
  const int tid = threadIdx.x;
  const int rb = wg >> 2, cb = wg & 3;
  if (s > 0) {
    if (tid < 128) {
      const int lrow = tid >> 1, j = tid & 1;
      const int row = rb * 64 + lrow;
      const int rotp = s * 2 - 1;
      float mean, rstd;
      ln_stats(p.pst3rot + rotp * 1024, row, mean, rstd);
      const float* yr = p.Y3rot + rotp * 32768 + row * 256;
      const float* wr = p.out_W + j * 256;
      const float* g3 = p.ln3_g + 256;
      const float* b3 = p.ln3_b + 256;
      float a = 0.f;
      for (int k = 0; k < 256; k += 4) {
        float4 y = *(const float4*)(yr + k);
        float4 gg = *(const float4*)(g3 + k);
        float4 bb = *(const float4*)(b3 + k);
        float4 ww = *(const float4*)(wr + k);
        a += ((y.x - mean) * rstd * gg.x + bb.x) * ww.x
           + ((y.y - mean) * rstd * gg.y + bb.y) * ww.y
           + ((y.z - mean) * rstd * gg.z + bb.z) * ww.z
           + ((y.w - mean) * rstd * gg.w + bb.w) * ww.w;
      }
      a += p.out_b[j];
      if (cb == 0) p.out[((s - 1) * AGENTS + row) * 2 + j] = a;
      sscene[lrow][j] += a;
    }
  } else {
    if (tid < 128)
      sscene[tid >> 1][tid & 1] = p.last_pos[(rb * 64 + (tid >> 1)) * 2 + (tid & 1)];
  }
  __syncthreads();
  if (s == PRED) return;

  const int l = tid & 63, w = tid >> 6;
  const int c15 = l & 15, g8 = (l >> 4) * 8, r0v = (l >> 4) * 4;
  const int rowb = rb * 64 + w * 16;
  const int arow = rowb + c15;
  const int lsrow = w * 16 + c15;
  const int colb = cb * 64;
  f32x4 acc[4] = {};
  const unsigned short* wp = p.inWb + (colb + c15) * 160 + g8;
  for (int kc = 0; kc < 5; ++kc) {
    short8 af;
#pragma unroll
    for (int j = 0; j < 8; ++j) {
      int kk = kc * 32 + g8 + j;
      float v = (kk < 2) ? sscene[lsrow][kk]
                         : ((kk < 130) ? p.ds[arow * 128 + (kk - 2)] : 0.f);
      af[j] = (short)f2bf(v);
    }
#pragma unroll
    for (int t = 0; t < 4; ++t)
      acc[t] = MFMA(af, *(const short8*)(wp + t * 16 * 160 + kc * 32), acc[t]);
  }
  float* x0 = p.x0rot + s * 32768;
  unsigned short* xb0 = p.xb0rot + s * 32768;
#pragma unroll
  for (int t = 0; t < 4; ++t) {
    const int col = colb + t * 16 + c15;
    const float bb = p.in_b[col] + p.peT[s * DIM + col];
#pragma unroll
    for (int r = 0; r < 4; ++r) {
      const int row = rowb + r0v + r;
      float v = acc[t][r] + bb + p.peA[row * DIM + col];
      ast(&x0[row * DIM + col], v);
      ast(&xb0[row * DIM + col], f2bf(v));
    }
  }
}

// ---------------------------------------------------------------------------
// Phase: SA Q/K/V projections. WGs 0..7 = Q; WGs 8..15 = K AND V.
// li==0: A = xb0rot[s] (bf16); li==1: A = LN3_l0(Y3rot[rot-1]).
// ---------------------------------------------------------------------------
__device__ void ph_qkv(const MegaP& p, int wg, int s, int li) {
  const bool isQ = wg < 8;
  const int t8 = isQ ? wg : (wg - 8);
  const int rb = t8 >> 2, cb = t8 & 3;
  const int tid = threadIdx.x, l = tid & 63, w = tid >> 6;
  const int c15 = l & 15, g8 = (l >> 4) * 8, r0v = (l >> 4) * 4;
  const int rowb = rb * 64 + w * 16;
  const int arow = rowb + c15;
  const int colb = cb * 64;
  const int rot = s * 2 + li;

  const unsigned short* ab = p.xb0rot + s * 32768;
  const float* Ya = p.Y3rot + (rot - 1) * 32768;
  float mean = 0.f, rstd = 0.f;
  if (li == 1) ln_stats(p.pst3rot + (rot - 1) * 1024, arow, mean, rstd);

  short8 af[8];
#pragma unroll
  for (int kc = 0; kc < 8; ++kc)
    af[kc] = (li == 0) ? *(const short8*)(ab + arow * 256 + kc * 32 + g8)
                       : afragLN(Ya + arow * 256, p.ln3_g, p.ln3_b,
                                 kc * 32 + g8, mean, rstd);

  if (isQ) {
    const unsigned short* W = p.dxdb + li * 65536;
    const float* bias = p.sa_bq + li * 256;
    f32x4 acc[4] = {};
    const unsigned short* wp = W + (colb + c15) * 256 + g8;
#pragma unroll
    for (int kc = 0; kc < 8; ++kc)
#pragma unroll
      for (int t = 0; t < 4; ++t)
        acc[t] = MFMA(af[kc], *(const short8*)(wp + t * 16 * 256 + kc * 32), acc[t]);
    unsigned short* qdst = p.qrot + rot * 32768;
#pragma unroll
    for (int t = 0; t < 4; ++t) {
      int col = colb + t * 16 + c15;
      float bb = bias[col];
#pragma unroll
      for (int r = 0; r < 4; ++r)
        ast(&qdst[(rowb + r0v + r) * 256 + col], f2bf(acc[t][r] + bb));
    }
  } else {
    const unsigned short* Wk = p.dxdb + 1 * 131072 + li * 65536;
    const unsigned short* Wv = p.dxdb + 2 * 131072 + li * 65536;
    const float* bk = p.sa_bk + li * 256;
    const float* bv = p.sa_bv + li * 256;
    f32x4 ak[4] = {}, av[4] = {};
    const unsigned short* wpk = Wk + (colb + c15) * 256 + g8;
    const unsigned short* wpv = Wv + (colb + c15) * 256 + g8;
#pragma unroll
    for (int kc = 0; kc < 8; ++kc)
#pragma unroll
      for (int t = 0; t < 4; ++t) {
        ak[t] = MFMA(af[kc], *(const short8*)(wpk + t * 16 * 256 + kc * 32), ak[t]);
        av[t] = MFMA(af[kc], *(const short8*)(wpv + t * 16 * 256 + kc * 32), av[t]);
      }
    unsigned short* Ko = p.saK + li * 393216;
    unsigned short* Vo = p.saV + li * 393216;
    const int kb = s * 8 + rb * 4 + w;
#pragma unroll
    for (int t = 0; t < 4; ++t) {
      int col = colb + t * 16 + c15;
      float bbk = bk[col], bbv = bv[col];
      int hh = col >> 5, d = col & 31;
#pragma unroll
      for (int r = 0; r < 4; ++r)
        ast(&Ko[hh * (MAXS * 32) + (s * 128 + rowb + r0v + r) * 32 + d],
            f2bf(ak[t][r] + bbk));
      unsigned long long pk = 0;
#pragma unroll
      for (int r = 0; r < 4; ++r)
        pk |= (unsigned long long)f2bf(av[t][r] + bbv) << (16 * r);
      ast((unsigned long long*)&Vo[(kb * 256 + col) * 16 + r0v], pk);
    }
  }
}

// ---------------------------------------------------------------------------
// Phase: SA attention. WGs 0..15 = (rb, head). Reads qrot; writes abufrot.
// ---------------------------------------------------------------------------
__device__ void ph_attn_sa(const MegaP& p, unsigned short (*ps)[16][96],
                           int wg, int s, int li) {
  const int rb = wg >> 3, h = wg & 7;
  const int tid = threadIdx.x, l = tid & 63, w = tid >> 6;
  const int c15 = l & 15, g = l >> 4, g8 = g * 8;
  const int rot = s * 2 + li;
  const int qrow = rb * 64 + w * 16 + c15;
  const int S = (s + 1) * 128;

  short8 qf = *(const short8*)(p.qrot + rot * 32768 + qrow * 256 + h * 32 + g8);
  float mk[2][4][4];
#pragma unroll
  for (int pp = 0; pp < 2; ++pp)
#pragma unroll
    for (int t = 0; t < 4; ++t)
#pragma unroll
      for (int r = 0; r < 4; ++r)
        mk[pp][t][r] = p.mask[qrow * AGENTS + pp * 64 + t * 16 + g * 4 + r];

  f32x4 oa0 = {}, oa1 = {};
  float lsum = 0.f;
  flash64(p.saK + li * 393216 + h * (MAXS * 32), p.saV + li * 393216,
          h * 32, qf, mk, S, &ps[w][c15][0], c15, g8, g, lsum, oa0, oa1);
  lsum += __shfl_xor(lsum, 16, 64);
  lsum += __shfl_xor(lsum, 32, 64);
  const float inv = 1.0f / lsum;
  unsigned long long pk0 = 0, pk1 = 0;
#pragma unroll
  for (int r = 0; r < 4; ++r) {
    pk0 |= (unsigned long long)f2bf(oa0[r] * inv) << (16 * r);
    pk1 |= (unsigned long long)f2bf(oa1[r] * inv) << (16 * r);
  }
  unsigned short* adst = p.abufrot + rot * 32768;
  ast((unsigned long long*)(adst + h * 4096 + qrow * 32 + g * 4), pk0);
  ast((unsigned long long*)(adst + h * 4096 + qrow * 32 + 16 + g * 4), pk1);
}

// ---------------------------------------------------------------------------
// Phase: CA attention + fused Q-proj from LN1(Y1). WGs 0..15 = (rb, head).
// ---------------------------------------------------------------------------
__device__ void ph_attn_ca(const MegaP& p, unsigned short (*sq)[16][32],
                           unsigned short (*ps)[16][96], int wg, int s, int li) {
  const int rb = wg >> 3, h = wg & 7;
  const int tid = threadIdx.x, l = tid & 63, w = tid >> 6;
  const int c15 = l & 15, g = l >> 4, g8 = g * 8, r0v = g * 4;
  const int rot = s * 2 + li;
  const int rowb = rb * 64 + w * 16;
  const int arow = rowb + c15;

  const float* Ya = p.Y1rot + rot * 32768;
  const float* lga = p.ln1_g + li * 256;
  const float* lba = p.ln1_b + li * 256;
  float mean, rstd;
  ln_stats(p.pst1rot + rot * 1024, arow, mean, rstd);

  const unsigned short* Wq = p.dxdb + 4 * 131072 + li * 65536;
  const float* bq = p.ca_bq + li * 256;
  f32x4 q0 = {}, q1 = {};
  const unsigned short* wp = Wq + (h * 32 + c15) * 256 + g8;
  for (int kc = 0; kc < 8; ++kc) {
    short8 af = afragLN(Ya + arow * 256, lga, lba, kc * 32 + g8, mean, rstd);
    q0 = MFMA(af, *(const short8*)(wp + kc * 32), q0);
    q1 = MFMA(af, *(const short8*)(wp + 16 * 256 + kc * 32), q1);
  }
  {
    const float b0 = bq[h * 32 + c15], b1 = bq[h * 32 + 16 + c15];
#pragma unroll
    for (int r = 0; r < 4; ++r) {
      sq[w][r0v + r][c15]      = f2bf(q0[r] + b0);
      sq[w][r0v + r][16 + c15] = f2bf(q1[r] + b1);
    }
  }
  short8 qf = *(const short8*)&sq[w][c15][g8];   // wave-private

  float mk[2][4][4];
#pragma unroll
  for (int pp = 0; pp < 2; ++pp)
#pragma unroll
    for (int t = 0; t < 4; ++t)
#pragma unroll
      for (int r = 0; r < 4; ++r)
        mk[pp][t][r] = p.mask[arow * AGENTS + pp * 64 + t * 16 + g * 4 + r];

  f32x4 oa0 = {}, oa1 = {};
  float lsum = 0.f;
  flash64(p.memK + li * 262144 + h * (MEM_LEN * 32), p.memV + li * 262144,
          h * 32, qf, mk, MEM_LEN, &ps[w][c15][0], c15, g8, g, lsum, oa0, oa1);
  lsum += __shfl_xor(lsum, 16, 64);
  lsum += __shfl_xor(lsum, 32, 64);
  const float inv = 1.0f / lsum;
  unsigned long long pk0 = 0, pk1 = 0;
#pragma unroll
  for (int r = 0; r < 4; ++r) {
    pk0 |= (unsigned long long)f2bf(oa0[r] * inv) << (16 * r);
    pk1 |= (unsigned long long)f2bf(oa1[r] * inv) << (16 * r);
  }
  unsigned short* adst = p.cabufrot + rot * 32768;
  ast((unsigned long long*)(adst + h * 4096 + arow * 32 + g * 4), pk0);
  ast((unsigned long long*)(adst + h * 4096 + arow * 32 + 16 + g * 4), pk1);
}

// ---------------------------------------------------------------------------
// Phase: 64x64 out-projection + residual + pst. WGs 0..7.
// ALAY 0: A = attn layout [8][128][32], K=256; ALAY 1: A = [128][1024], K=1024.
// RES 1: + fp32 res; RES 2: + LN(Yp,pstp,gp,bp).
// ---------------------------------------------------------------------------
template <int ALAY, int RES>
__device__ void ph_oproj(const MegaP& p, int wg,
    const unsigned short* __restrict__ ab,
    const unsigned short* __restrict__ W, const float* __restrict__ bias,
    const float* __restrict__ res,
    const float* __restrict__ Yp, const float* __restrict__ pstp,
    const float* __restrict__ gp, const float* __restrict__ bp,
    float* __restrict__ Yo, float* __restrict__ psto)
{
  if (wg >= 8) return;
  const int tid = threadIdx.x, l = tid & 63, w = tid >> 6;
  const int c15 = l & 15, g8 = (l >> 4) * 8, r0v = (l >> 4) * 4;
  const int rowb = (wg >> 2) * 64 + w * 16;
  const int arow = rowb + c15;
  const int cb = wg & 3, colb = cb * 64;
  constexpr int K = ALAY ? 1024 : 256;

  f32x4 acc[4] = {};
  const unsigned short* wp = W + (colb + c15) * K + g8;
  for (int kc = 0; kc < K / 32; ++kc) {
    short8 af;
    if (ALAY == 0) af = *(const short8*)(ab + kc * 4096 + arow * 32 + g8);
    else           af = *(const short8*)(ab + arow * 1024 + kc * 32 + g8);
#pragma unroll
    for (int t = 0; t < 4; ++t)
      acc[t] = MFMA(af, *(const short8*)(wp + t * 16 * K + kc * 32), acc[t]);
  }

  float mp[4], rp[4];
  if (RES == 2) {
#pragma unroll
    for (int r = 0; r < 4; ++r) ln_stats(pstp, rowb + r0v + r, mp[r], rp[r]);
  }
  float v[4][4];
#pragma unroll
  for (int t = 0; t < 4; ++t) {
    const int col = colb + t * 16 + c15;
    const float bb = bias[col];
    float gpp = 0.f, bpp = 0.f;
    if (RES == 2) { gpp = gp[col]; bpp = bp[col]; }
#pragma unroll
    for (int r = 0; r < 4; ++r) {
      const int row = rowb + r0v + r;
      float x = acc[t][r] + bb;
      if (RES == 1) x += res[row * 256 + col];
      if (RES == 2) x += (Yp[row * 256 + col] - mp[r]) * rp[r] * gpp + bpp;
      ast(&Yo[row * 256 + col], x);
      v[t][r] = x;
    }
  }
#pragma unroll
  for (int r = 0; r < 4; ++r) {
    float s  = v[0][r] + v[1][r] + v[2][r] + v[3][r];
    float ss = v[0][r]*v[0][r] + v[1][r]*v[1][r] + v[2][r]*v[2][r] + v[3][r]*v[3][r];
#pragma unroll
    for (int m = 1; m < 16; m <<= 1) {
      s  += __shfl_xor(s, m, 64);
      ss += __shfl_xor(ss, m, 64);
    }
    if (c15 == 0) {
      const int row = rowb + r0v + r;
      ast(&psto[row * 8 + cb * 2], s);
      ast(&psto[row * 8 + cb * 2 + 1], ss);
    }
  }
}

// ---------------------------------------------------------------------------
// Phase: FF1 (LN2(Y2) @ W1 + relu -> midrot). WGs 0..15 (2 rb x 8 cb of 128).
// ---------------------------------------------------------------------------
__device__ void ph_ff1(const MegaP& p, int wg, int s, int li) {
  const int rb = wg >> 3, cb = wg & 7;
  const int tid = threadIdx.x, l = tid & 63, w = tid >> 6;
  const int c15 = l & 15, g8 = (l >> 4) * 8, r0v = (l >> 4) * 4;
  const int rowb = rb * 64 + w * 16;
  const int arow = rowb + c15;
  const int colb = cb * 128;
  const int rot = s * 2 + li;

  const float* Ya = p.Y2rot + rot * 32768;
  const float* lga = p.ln2_g + li * 256;
  const float* lba = p.ln2_b + li * 256;
  float mean, rstd;
  ln_stats(p.pst2rot + rot * 1024, arow, mean, rstd);

  const unsigned short* W1 = p.ffW1b + li * 262144;
  const float* b1 = p.ff_b1 + li * 1024;
  f32x4 acc[8] = {};
  const unsigned short* wp = W1 + (colb + c15) * 256 + g8;
  for (int kc = 0; kc < 8; ++kc) {
    short8 af = afragLN(Ya + arow * 256, lga, lba, kc * 32 + g8, mean, rstd);
#pragma unroll
    for (int t = 0; t < 8; ++t)
      acc[t] = MFMA(af, *(const short8*)(wp + t * 16 * 256 + kc * 32), acc[t]);
  }
  unsigned short* mid = p.midrot + rot * 131072;
#pragma unroll
  for (int t = 0; t < 8; ++t) {
    const int col = colb + t * 16 + c15;
    const float bb = b1[col];
#pragma unroll
    for (int r = 0; r < 4; ++r)
      ast(&mid[(rowb + r0v + r) * 1024 + col], f2bf(fmaxf(acc[t][r] + bb, 0.f)));
  }
}

// ---------------------------------------------------------------------------
// THE mega kernel: persistent, 16 WGs, col-partitioned weight-stationary.
// ---------------------------------------------------------------------------
__global__ __launch_bounds__(256, 1) void mega_k(MegaP p) {
  __shared__ float sscene[64][2];
  __shared__ unsigned short sq[4][16][32];
  __shared__ unsigned short ps[4][16][96];
  const int wg = blockIdx.x;
  unsigned tgt = 0;
#define GB gridbar(p.barCnt, tgt)

  for (int s = 0; s < PRED; ++s) {
    ph_embed(p, wg, s, sscene);
    GB;
    for (int li = 0; li < 2; ++li) {
      const int rot = s * 2 + li;
      ph_qkv(p, wg, s, li);
      GB;
      ph_attn_sa(p, ps, wg, s, li);
      GB;
      if (li == 0)
        ph_oproj<0, 1>(p, wg, p.abufrot + rot * 32768,
                       p.dxdb + 3 * 131072, p.sa_bo,
                       p.x0rot + s * 32768, nullptr, nullptr, nullptr, nullptr,
                       p.Y1rot + rot * 32768, p.pst1rot + rot * 1024);
      else
        ph_oproj<0, 2>(p, wg, p.abufrot + rot * 32768,
                       p.dxdb + 3 * 131072 + 65536, p.sa_bo + 256,
                       nullptr, p.Y3rot + (rot - 1) * 32768,
                       p.pst3rot + (rot - 1) * 1024, p.ln3_g, p.ln3_b,
                       p.Y1rot + rot * 32768, p.pst1rot + rot * 1024);
      GB;
      ph_attn_ca(p, sq, ps, wg, s, li);
      GB;
      ph_oproj<0, 2>(p, wg, p.cabufrot + rot * 32768,
                     p.dxdb + 7 * 131072 + li * 65536, p.ca_bo + li * 256,
                     nullptr, p.Y1rot + rot * 32768, p.pst1rot + rot * 1024,
                     p.ln1_g + li * 256, p.ln1_b + li * 256,
                     p.Y2rot + rot * 32768, p.pst2rot + rot * 1024);
      GB;
      ph_ff1(p, wg, s, li);
      GB;
      ph_oproj<1, 2>(p, wg, p.midrot + rot * 131072,
                     p.ffW2b + li * 262144, p.ff_b2 + li * 256,
                     nullptr, p.Y2rot + rot * 32768, p.pst2rot + rot * 1024,
                     p.ln2_g + li * 256, p.ln2_b + li * 256,
                     p.Y3rot + rot * 32768, p.pst3rot + rot * 1024);
      GB;
    }
  }
  ph_embed(p, wg, PRED, sscene);   // final out-projection
#undef GB
}

// ---------------------------------------------------------------------------
// Prologue kernels
// ---------------------------------------------------------------------------
__global__ void cvt8_k(const float* p0, const float* p1, const float* p2,
                       const float* p3, const float* p4, const float* p5,
                       const float* p6, const float* p7, unsigned short* dst)
{
  const float* s;
  switch (blockIdx.z) {
    case 0: s = p0; break; case 1: s = p1; break;
    case 2: s = p2; break; case 3: s = p3; break;
    case 4: s = p4; break; case 5: s = p5; break;
    case 6: s = p6; break; default: s = p7; break;
  }
  int i = blockIdx.x * 256 + threadIdx.x;
  dst[blockIdx.z * 131072 + i] = f2bf(s[i]);
}

__global__ void cvtff_k(const float* w1, const float* w2, unsigned short* dst)
{
  const float* s = blockIdx.z ? w2 : w1;
  int i = blockIdx.x * 256 + threadIdx.x;
  dst[blockIdx.z * 524288 + i] = f2bf(s[i]);
}

__global__ void cvtinw_k(const float* w, unsigned short* dst)
{
  int i = blockIdx.x * 256 + threadIdx.x;
  if (i >= 256 * 160) return;
  int n = i / 160, k = i - n * 160;
  dst[i] = (k < 130) ? f2bf(w[n * 130 + k]) : (unsigned short)0;
}

__global__ void pe_k(float* peA, float* peT)
{
  int i = blockIdx.x * 256 + threadIdx.x;
  if (i < 128 * 256) {
    int row = i >> 8, c = i & 255, pp = c >> 1;
    float dv = expf((float)(2 * pp) * (-9.210340371976184f / 256.f));
    float ang = (float)row * dv;
    peA[i] = (c & 1) ? cosf(ang) : sinf(ang);
  } else if (i < 140 * 256) {
    int j = i - 32768;
    int s = j >> 8, c = j & 255, pp = c >> 1;
    float dv = expf((float)(2 * pp) * (-9.210340371976184f / 256.f));
    float ang = (float)s * dv;
    peT[j] = (c & 1) ? cosf(ang) : sinf(ang);
  }
}

// memory K/V precompute; V blocked [kb][256][16]. Grid (16, 8, 2).
__global__ __launch_bounds__(256) void memkv_k(
    const float* __restrict__ mem, const unsigned short* __restrict__ dxd,
    const float* __restrict__ bk, const float* __restrict__ bvv,
    unsigned short* __restrict__ memK, unsigned short* __restrict__ memV)
{
  const int li = blockIdx.z;
  const int y = blockIdx.y;
  const bool isK = y < 4;
  const int colb = (y & 3) * 64;
  const unsigned short* W = dxd + (isK ? 5 : 6) * 131072 + li * 65536;
  const float* bias = (isK ? bk : bvv) + li * 256;
  unsigned short* Ko = memK + li * 262144;
  unsigned short* Vo = memV + li * 262144;
  const int tid = threadIdx.x, l = tid & 63, w = tid >> 6;
  const int c15 = l & 15, g8 = (l >> 4) * 8, r0v = (l >> 4) * 4;
  const int rowb = blockIdx.x * 64 + w * 16;
  const int arow = rowb + c15;
  f32x4 acc[4] = {};
  const unsigned short* wp = W + (colb + c15) * 256 + g8;
  for (int kc = 0; kc < 8; ++kc) {
    short8 af = afrag8(mem + arow * 256 + kc * 32 + g8);
#pragma unroll
    for (int t = 0; t < 4; ++t)
      acc[t] = MFMA(af, *(const short8*)(wp + t * 16 * 256 + kc * 32), acc[t]);
  }
  const int kb = blockIdx.x * 4 + w;
#pragma unroll
  for (int t = 0; t < 4; ++t) {
    const int col = colb + t * 16 + c15;
    const float bb = bias[col];
    if (isK) {
      const int hh = col >> 5, d = col & 31;
#pragma unroll
      for (int r = 0; r < 4; ++r)
        Ko[hh * (MEM_LEN * 32) + (rowb + r0v + r) * 32 + d] = f2bf(acc[t][r] + bb);
    } else {
      unsigned long long pk = 0;
#pragma unroll
      for (int r = 0; r < 4; ++r)
        pk |= (unsigned long long)f2bf(acc[t][r] + bb) << (16 * r);
      *(unsigned long long*)&Vo[(kb * 256 + col) * 16 + r0v] = pk;
    }
  }
}

__global__ void initbar_k(unsigned* b) { b[0] = 0; }

// ---------------------------------------------------------------------------
extern "C" void kernel_launch(void* const* d_in, const int* in_sizes, int n_in,
                              void* d_out, int out_size, void* d_ws, size_t ws_size,
                              hipStream_t stream)
{
  // workspace layout (~30 MB)
  float* ws = (float*)d_ws;
  float* peA = ws;                            // 32768
  float* peT = peA + 32768;                   // 3072
  float* x0rot = peT + 3072;                  // 12*32768
  float* Y1rot = x0rot + 393216;              // 24*32768
  float* Y2rot = Y1rot + 786432;
  float* Y3rot = Y2rot + 786432;
  float* pst1rot = Y3rot + 786432;            // 24*1024
  float* pst2rot = pst1rot + 24576;
  float* pst3rot = pst2rot + 24576;
  unsigned short* xb0rot = (unsigned short*)(pst3rot + 24576);  // 12*32768
  unsigned short* qrot = xb0rot + 393216;     // 24*32768
  unsigned short* abufrot = qrot + 786432;
  unsigned short* cabufrot = abufrot + 786432;
  unsigned short* midrot = cabufrot + 786432; // 24*131072
  unsigned short* saK = midrot + 3145728;     // 2*393216
  unsigned short* saV = saK + 786432;
  unsigned short* memK = saV + 786432;        // 2*262144
  unsigned short* memV = memK + 524288;
  unsigned short* dxdb = memV + 524288;       // 8*131072
  unsigned short* ffW1b = dxdb + 1048576;     // 524288
  unsigned short* ffW2b = ffW1b + 524288;
  unsigned short* inWb = ffW2b + 524288;      // 40960
  unsigned* bar = (unsigned*)(inWb + 40960);

  const dim3 blk(256);

  cvt8_k<<<dim3(512, 1, 8), blk, 0, stream>>>(
      (const float*)d_in[8], (const float*)d_in[10], (const float*)d_in[12],
      (const float*)d_in[14], (const float*)d_in[16], (const float*)d_in[18],
      (const float*)d_in[20], (const float*)d_in[22], dxdb);
  cvtff_k<<<dim3(2048, 1, 2), blk, 0, stream>>>((const float*)d_in[24],
                                                (const float*)d_in[26], ffW1b);
  cvtinw_k<<<160, blk, 0, stream>>>((const float*)d_in[4], inWb);
  pe_k<<<140, blk, 0, stream>>>(peA, peT);
  memkv_k<<<dim3(16, 8, 2), blk, 0, stream>>>((const float*)d_in[2], dxdb,
      (const float*)d_in[19], (const float*)d_in[21], memK, memV);
  initbar_k<<<1, 1, 0, stream>>>(bar);

  MegaP p;
  p.last_pos = (const float*)d_in[0];
  p.ds = (const float*)d_in[1];
  p.mask = (const float*)d_in[3];
  p.in_b = (const float*)d_in[5];
  p.out_W = (const float*)d_in[6];
  p.out_b = (const float*)d_in[7];
  p.sa_bq = (const float*)d_in[9];  p.sa_bk = (const float*)d_in[11];
  p.sa_bv = (const float*)d_in[13]; p.sa_bo = (const float*)d_in[15];
  p.ca_bq = (const float*)d_in[17]; p.ca_bo = (const float*)d_in[23];
  p.ff_b1 = (const float*)d_in[25]; p.ff_b2 = (const float*)d_in[27];
  p.ln1_g = (const float*)d_in[28]; p.ln1_b = (const float*)d_in[29];
  p.ln2_g = (const float*)d_in[30]; p.ln2_b = (const float*)d_in[31];
  p.ln3_g = (const float*)d_in[32]; p.ln3_b = (const float*)d_in[33];
  p.out = (float*)d_out;
  p.peA = peA; p.peT = peT;
  p.x0rot = x0rot; p.xb0rot = xb0rot;
  p.qrot = qrot; p.abufrot = abufrot; p.cabufrot = cabufrot;
  p.Y1rot = Y1rot; p.Y2rot = Y2rot; p.Y3rot = Y3rot;
  p.pst1rot = pst1rot; p.pst2rot = pst2rot; p.pst3rot = pst3rot;
  p.midrot = midrot;
  p.saK = saK; p.saV = saV; p.memK = memK; p.memV = memV;
  p.dxdb = dxdb; p.ffW1b = ffW1b; p.ffW2b = ffW2b; p.inWb = inWb;
  p.barCnt = bar;

  mega_k<<<dim3(NWG), blk, 0, stream>>>(p);
}

// Round 12
// 3334.575 us; speedup vs baseline: 1.0766x; 1.0766x over previous
//
#include <hip/hip_runtime.h>
#include <math.h>

#define AGENTS 128
#define DIM 256
#define MEM_LEN 1024
#define PRED 12
#define MAXS (PRED * AGENTS)   // 1536
#define NWG 32

typedef __attribute__((ext_vector_type(8))) short short8;
typedef __attribute__((ext_vector_type(4))) float f32x4;

#define MFMA(a, b, c) __builtin_amdgcn_mfma_f32_16x16x32_bf16(a, b, c, 0, 0, 0)

__device__ __forceinline__ unsigned short f2bf(float f) {
  union { float f; unsigned u; } v; v.f = f;
  unsigned r = v.u + 0x7fffu + ((v.u >> 16) & 1u);   // RNE
  return (unsigned short)(r >> 16);
}
__device__ __forceinline__ float bfval(unsigned short b) {
  union { unsigned u; float f; } v; v.u = (unsigned)b << 16; return v.f;
}
__device__ __forceinline__ short8 afrag8(const float* p) {
  float4 a = *(const float4*)p;
  float4 b = *(const float4*)(p + 4);
  short8 r;
  r[0] = (short)f2bf(a.x); r[1] = (short)f2bf(a.y);
  r[2] = (short)f2bf(a.z); r[3] = (short)f2bf(a.w);
  r[4] = (short)f2bf(b.x); r[5] = (short)f2bf(b.y);
  r[6] = (short)f2bf(b.z); r[7] = (short)f2bf(b.w);
  return r;
}

// relaxed agent-scope store: sc1 write-through to coherence point, NO wbl2/inv
template <typename T>
__device__ __forceinline__ void ast(T* p, T v) {
  __hip_atomic_store(p, v, __ATOMIC_RELAXED, __HIP_MEMORY_SCOPE_AGENT);
}

// LN stats from 4 col-block partials pst[row][cb]=(sum,sumsq)
__device__ __forceinline__ void ln_stats(const float* __restrict__ pst, int row,
                                         float& mean, float& rstd) {
  float4 p0 = *(const float4*)(pst + row * 8);
  float4 p1 = *(const float4*)(pst + row * 8 + 4);
  float s  = p0.x + p0.z + p1.x + p1.z;
  float ss = p0.y + p0.w + p1.y + p1.w;
  mean = s * (1.0f / 256.0f);
  rstd = rsqrtf(ss * (1.0f / 256.0f) - mean * mean + 1e-5f);
}

__device__ __forceinline__ short8 afragLN(const float* __restrict__ yr,
                                          const float* __restrict__ lg,
                                          const float* __restrict__ lb,
                                          int k, float mean, float rstd) {
  float4 a = *(const float4*)(yr + k), b = *(const float4*)(yr + k + 4);
  float4 ga = *(const float4*)(lg + k), gb = *(const float4*)(lg + k + 4);
  float4 ba = *(const float4*)(lb + k), bb = *(const float4*)(lb + k + 4);
  short8 r;
  r[0] = (short)f2bf((a.x - mean) * rstd * ga.x + ba.x);
  r[1] = (short)f2bf((a.y - mean) * rstd * ga.y + ba.y);
  r[2] = (short)f2bf((a.z - mean) * rstd * ga.z + ba.z);
  r[3] = (short)f2bf((a.w - mean) * rstd * ga.w + ba.w);
  r[4] = (short)f2bf((b.x - mean) * rstd * gb.x + bb.x);
  r[5] = (short)f2bf((b.y - mean) * rstd * gb.y + bb.y);
  r[6] = (short)f2bf((b.z - mean) * rstd * gb.z + bb.z);
  r[7] = (short)f2bf((b.w - mean) * rstd * gb.w + bb.w);
  return r;
}

// ---------------------------------------------------------------------------
struct MegaP {
  const float *last_pos, *ds, *mask;
  const float *in_b, *out_W, *out_b;
  const float *sa_bq, *sa_bk, *sa_bv, *sa_bo;
  const float *ca_bq, *ca_bo;
  const float *ff_b1, *ff_b2;
  const float *ln1_g, *ln1_b, *ln2_g, *ln2_b, *ln3_g, *ln3_b;
  float *out;
  const float *peA, *peT;
  float *x0rot;                        // 12 x [128][256] fp32
  unsigned short *xb0rot;              // 12 x [128][256] bf16
  unsigned short *qrot, *abufrot, *cabufrot;  // 24 x 32768 bf16 each
  float *Y1rot, *Y2rot, *Y3rot;        // 24 x 32768 fp32 each
  float *pst1rot, *pst2rot, *pst3rot;  // 24 x 1024 fp32 each
  unsigned short *midrot;              // 24 x [128][1024] bf16
  unsigned short *saK, *saV;           // per layer: K [8][1536][32], V blocked [96][256][16]
  const unsigned short *memK, *memV;   // per layer: K [8][1024][32], V blocked [64][256][16]
  const unsigned short *dxdb, *ffW1b, *ffW2b, *inWb;
  unsigned *barCnt;
};

// Fully-relaxed monotonic grid barrier. Safe because all cross-WG data is
// written with sc1 write-through stores and hipcc drains vmcnt(0) before
// s_barrier, so data is at the coherence point before the counter RMW issues.
// No buffer_wbl2, no buffer_inv anywhere in the loop.
__device__ __forceinline__ void gridbar(unsigned* cnt, unsigned& tgt) {
  __syncthreads();
  tgt += NWG;
  if (threadIdx.x == 0) {
    unsigned old = __hip_atomic_fetch_add(cnt, 1u, __ATOMIC_RELAXED,
                                          __HIP_MEMORY_SCOPE_AGENT);
    if (old + 1u < tgt) {
      while (__hip_atomic_load(cnt, __ATOMIC_RELAXED,
                               __HIP_MEMORY_SCOPE_AGENT) < tgt)
        __builtin_amdgcn_s_sleep(1);
    }
  }
  __syncthreads();
  asm volatile("" ::: "memory");
}

// one 16-key score tile: MFMA -> exp -> bf16 pack + lsum
__device__ __forceinline__ void score_tile(short8 kf, short8 qf, const float* m4,
                                           unsigned short* dst, float& lsum) {
  const float scale = 0.17677669529663687f;
  f32x4 zz = {};
  f32x4 sc = MFMA(kf, qf, zz);
  unsigned short b0 = f2bf(__expf(sc[0] * scale + m4[0]));
  unsigned short b1 = f2bf(__expf(sc[1] * scale + m4[1]));
  unsigned short b2 = f2bf(__expf(sc[2] * scale + m4[2]));
  unsigned short b3 = f2bf(__expf(sc[3] * scale + m4[3]));
  lsum += bfval(b0) + bfval(b1) + bfval(b2) + bfval(b3);
  uint2 u2;
  u2.x = (unsigned)b0 | ((unsigned)b1 << 16);
  u2.y = (unsigned)b2 | ((unsigned)b3 << 16);
  *(uint2*)dst = u2;
}

// flash attention over S keys, one head, 16 queries per wave; V blocked.
__device__ __forceinline__ void flash64(const unsigned short* __restrict__ kh,
                                        const unsigned short* __restrict__ vbase,
                                        int hcol, short8 qf, const float mk[2][4][4],
                                        int S, unsigned short* psrow,
                                        int c15, int g8, int g,
                                        float& lsum, f32x4& oa0, f32x4& oa1) {
  for (int kc = 0; kc < S; kc += 64) {
    const int pp = (kc >> 6) & 1;
#pragma unroll
    for (int t = 0; t < 4; ++t) {
      short8 kf = *(const short8*)(kh + (kc + t * 16 + c15) * 32 + g8);
      score_tile(kf, qf, mk[pp][t], psrow + t * 16 + g * 4, lsum);
    }
#pragma unroll
    for (int ks = 0; ks < 2; ++ks) {
      short8 pf = *(const short8*)(psrow + ks * 32 + g8);
      int j = kc + ks * 32 + g8;
      const unsigned short* vb = vbase + (j >> 4) * 4096 + (j & 15);
      short8 v0 = *(const short8*)(vb + (hcol + c15) * 16);
      short8 v1 = *(const short8*)(vb + (hcol + c15 + 16) * 16);
      oa0 = MFMA(v0, pf, oa0);
      oa1 = MFMA(v1, pf, oa1);
    }
  }
}

// ---------------------------------------------------------------------------
// Phase: prev-step out-proj (row-local redundant) + embed GEMM. WGs 0..7.
// s==PRED: out-proj only.
// ---------------------------------------------------------------------------
__device__ void ph_embed(const MegaP& p, int wg, int s, float (*sscene)[2]) {
  if (wg >= 8) return;
  const int tid = threadIdx.x;
  const int rb = wg >> 2, cb = wg & 3;
  if (s > 0) {
    if (tid < 128) {
      const int lrow = tid >> 1, j = tid & 1;
      const int row = rb * 64 + lrow;
      const int rotp = s * 2 - 1;
      float mean, rstd;
      ln_stats(p.pst3rot + rotp * 1024, row, mean, rstd);
      const float* yr = p.Y3rot + rotp * 32768 + row * 256;
      const float* wr = p.out_W + j * 256;
      const float* g3 = p.ln3_g + 256;
      const float* b3 = p.ln3_b + 256;
      float a = 0.f;
      for (int k = 0; k < 256; k += 4) {
        float4 y = *(const float4*)(yr + k);
        float4 gg = *(const float4*)(g3 + k);
        float4 bb = *(const float4*)(b3 + k);
        float4 ww = *(const float4*)(wr + k);
        a += ((y.x - mean) * rstd * gg.x + bb.x) * ww.x
           + ((y.y - mean) * rstd * gg.y + bb.y) * ww.y
           + ((y.z - mean) * rstd * gg.z + bb.z) * ww.z
           + ((y.w - mean) * rstd * gg.w + bb.w) * ww.w;
      }
      a += p.out_b[j];
      if (cb == 0) p.out[((s - 1) * AGENTS + row) * 2 + j] = a;
      sscene[lrow][j] += a;
    }
  } else {
    if (tid < 128)
      sscene[tid >> 1][tid & 1] = p.last_pos[(rb * 64 + (tid >> 1)) * 2 + (tid & 1)];
  }
  __syncthreads();
  if (s == PRED) return;

  const int l = tid & 63, w = tid >> 6;
  const int c15 = l & 15, g8 = (l >> 4) * 8, r0v = (l >> 4) * 4;
  const int rowb = rb * 64 + w * 16;
  const int arow = rowb + c15;
  const int lsrow = w * 16 + c15;
  const int colb = cb * 64;
  f32x4 acc[4] = {};
  const unsigned short* wp = p.inWb + (colb + c15) * 160 + g8;
  for (int kc = 0; kc < 5; ++kc) {
    short8 af;
#pragma unroll
    for (int j = 0; j < 8; ++j) {
      int kk = kc * 32 + g8 + j;
      float v = (kk < 2) ? sscene[lsrow][kk]
                         : ((kk < 130) ? p.ds[arow * 128 + (kk - 2)] : 0.f);
      af[j] = (short)f2bf(v);
    }
#pragma unroll
    for (int t = 0; t < 4; ++t)
      acc[t] = MFMA(af, *(const short8*)(wp + t * 16 * 160 + kc * 32), acc[t]);
  }
  float* x0 = p.x0rot + s * 32768;
  unsigned short* xb0 = p.xb0rot + s * 32768;
#pragma unroll
  for (int t = 0; t < 4; ++t) {
    const int col = colb + t * 16 + c15;
    const float bb = p.in_b[col] + p.peT[s * DIM + col];
#pragma unroll
    for (int r = 0; r < 4; ++r) {
      const int row = rowb + r0v + r;
      float v = acc[t][r] + bb + p.peA[row * DIM + col];
      ast(&x0[row * DIM + col], v);
      ast(&xb0[row * DIM + col], f2bf(v));
    }
  }
}

// ---------------------------------------------------------------------------
// Phase: SA Q/K/V projections. WGs 0..23 (which = wg>>3: 0=Q,1=K,2=V).
// li==0: A = xb0rot[s] (bf16); li==1: A = LN3_l0(Y3rot[rot-1]).
// ---------------------------------------------------------------------------
__device__ void ph_qkv(const MegaP& p, int wg, int s, int li) {
  if (wg >= 24) return;
  const int which = wg >> 3, t8 = wg & 7;
  const int rb = t8 >> 2, cb = t8 & 3;
  const int tid = threadIdx.x, l = tid & 63, w = tid >> 6;
  const int c15 = l & 15, g8 = (l >> 4) * 8, r0v = (l >> 4) * 4;
  const int rowb = rb * 64 + w * 16;
  const int arow = rowb + c15;
  const int colb = cb * 64;
  const int rot = s * 2 + li;

  const unsigned short* ab = p.xb0rot + s * 32768;
  const float* Ya = p.Y3rot + (rot - 1) * 32768;
  float mean = 0.f, rstd = 0.f;
  if (li == 1) ln_stats(p.pst3rot + (rot - 1) * 1024, arow, mean, rstd);

  const unsigned short* W = p.dxdb + which * 131072 + li * 65536;
  const float* bias = (which == 0 ? p.sa_bq : (which == 1 ? p.sa_bk : p.sa_bv)) + li * 256;

  f32x4 acc[4] = {};
  const unsigned short* wp = W + (colb + c15) * 256 + g8;
  for (int kc = 0; kc < 8; ++kc) {
    short8 af = (li == 0) ? *(const short8*)(ab + arow * 256 + kc * 32 + g8)
                          : afragLN(Ya + arow * 256, p.ln3_g, p.ln3_b,
                                    kc * 32 + g8, mean, rstd);
#pragma unroll
    for (int t = 0; t < 4; ++t)
      acc[t] = MFMA(af, *(const short8*)(wp + t * 16 * 256 + kc * 32), acc[t]);
  }

  if (which == 0) {
    unsigned short* qdst = p.qrot + rot * 32768;
#pragma unroll
    for (int t = 0; t < 4; ++t) {
      int col = colb + t * 16 + c15;
      float bb = bias[col];
#pragma unroll
      for (int r = 0; r < 4; ++r)
        ast(&qdst[(rowb + r0v + r) * 256 + col], f2bf(acc[t][r] + bb));
    }
  } else if (which == 1) {
    unsigned short* Ko = p.saK + li * 393216;
#pragma unroll
    for (int t = 0; t < 4; ++t) {
      int col = colb + t * 16 + c15;
      float bb = bias[col];
      int hh = col >> 5, d = col & 31;
#pragma unroll
      for (int r = 0; r < 4; ++r)
        ast(&Ko[hh * (MAXS * 32) + (s * 128 + rowb + r0v + r) * 32 + d],
            f2bf(acc[t][r] + bb));
    }
  } else {
    unsigned short* Vo = p.saV + li * 393216;
    const int kb = s * 8 + rb * 4 + w;   // key-block of 16
#pragma unroll
    for (int t = 0; t < 4; ++t) {
      int col = colb + t * 16 + c15;
      float bb = bias[col];
      unsigned long long pk = 0;
#pragma unroll
      for (int r = 0; r < 4; ++r)
        pk |= (unsigned long long)f2bf(acc[t][r] + bb) << (16 * r);
      ast((unsigned long long*)&Vo[(kb * 256 + col) * 16 + r0v], pk);
    }
  }
}

// ---------------------------------------------------------------------------
// Phase: SA attention. WGs 0..15 = (rb, head). Reads qrot; writes abufrot.
// ---------------------------------------------------------------------------
__device__ void ph_attn_sa(const MegaP& p, unsigned short (*ps)[16][96],
                           int wg, int s, int li) {
  if (wg >= 16) return;
  const int rb = wg >> 3, h = wg & 7;
  const int tid = threadIdx.x, l = tid & 63, w = tid >> 6;
  const int c15 = l & 15, g = l >> 4, g8 = g * 8;
  const int rot = s * 2 + li;
  const int qrow = rb * 64 + w * 16 + c15;
  const int S = (s + 1) * 128;

  short8 qf = *(const short8*)(p.qrot + rot * 32768 + qrow * 256 + h * 32 + g8);
  float mk[2][4][4];
#pragma unroll
  for (int pp = 0; pp < 2; ++pp)
#pragma unroll
    for (int t = 0; t < 4; ++t)
#pragma unroll
      for (int r = 0; r < 4; ++r)
        mk[pp][t][r] = p.mask[qrow * AGENTS + pp * 64 + t * 16 + g * 4 + r];

  f32x4 oa0 = {}, oa1 = {};
  float lsum = 0.f;
  flash64(p.saK + li * 393216 + h * (MAXS * 32), p.saV + li * 393216,
          h * 32, qf, mk, S, &ps[w][c15][0], c15, g8, g, lsum, oa0, oa1);
  lsum += __shfl_xor(lsum, 16, 64);
  lsum += __shfl_xor(lsum, 32, 64);
  const float inv = 1.0f / lsum;
  unsigned long long pk0 = 0, pk1 = 0;
#pragma unroll
  for (int r = 0; r < 4; ++r) {
    pk0 |= (unsigned long long)f2bf(oa0[r] * inv) << (16 * r);
    pk1 |= (unsigned long long)f2bf(oa1[r] * inv) << (16 * r);
  }
  unsigned short* adst = p.abufrot + rot * 32768;
  ast((unsigned long long*)(adst + h * 4096 + qrow * 32 + g * 4), pk0);
  ast((unsigned long long*)(adst + h * 4096 + qrow * 32 + 16 + g * 4), pk1);
}

// ---------------------------------------------------------------------------
// Phase: CA attention + fused Q-proj from LN1(Y1). WGs 0..15 = (rb, head).
// ---------------------------------------------------------------------------
__device__ void ph_attn_ca(const MegaP& p, unsigned short (*sq)[16][32],
                           unsigned short (*ps)[16][96], int wg, int s, int li) {
  if (wg >= 16) return;
  const int rb = wg >> 3, h = wg & 7;
  const int tid = threadIdx.x, l = tid & 63, w = tid >> 6;
  const int c15 = l & 15, g = l >> 4, g8 = g * 8, r0v = g * 4;
  const int rot = s * 2 + li;
  const int rowb = rb * 64 + w * 16;
  const int arow = rowb + c15;

  const float* Ya = p.Y1rot + rot * 32768;
  const float* lga = p.ln1_g + li * 256;
  const float* lba = p.ln1_b + li * 256;
  float mean, rstd;
  ln_stats(p.pst1rot + rot * 1024, arow, mean, rstd);

  const unsigned short* Wq = p.dxdb + 4 * 131072 + li * 65536;
  const float* bq = p.ca_bq + li * 256;
  f32x4 q0 = {}, q1 = {};
  const unsigned short* wp = Wq + (h * 32 + c15) * 256 + g8;
  for (int kc = 0; kc < 8; ++kc) {
    short8 af = afragLN(Ya + arow * 256, lga, lba, kc * 32 + g8, mean, rstd);
    q0 = MFMA(af, *(const short8*)(wp + kc * 32), q0);
    q1 = MFMA(af, *(const short8*)(wp + 16 * 256 + kc * 32), q1);
  }
  {
    const float b0 = bq[h * 32 + c15], b1 = bq[h * 32 + 16 + c15];
#pragma unroll
    for (int r = 0; r < 4; ++r) {
      sq[w][r0v + r][c15]      = f2bf(q0[r] + b0);
      sq[w][r0v + r][16 + c15] = f2bf(q1[r] + b1);
    }
  }
  short8 qf = *(const short8*)&sq[w][c15][g8];   // wave-private

  float mk[2][4][4];
#pragma unroll
  for (int pp = 0; pp < 2; ++pp)
#pragma unroll
    for (int t = 0; t < 4; ++t)
#pragma unroll
      for (int r = 0; r < 4; ++r)
        mk[pp][t][r] = p.mask[arow * AGENTS + pp * 64 + t * 16 + g * 4 + r];

  f32x4 oa0 = {}, oa1 = {};
  float lsum = 0.f;
  flash64(p.memK + li * 262144 + h * (MEM_LEN * 32), p.memV + li * 262144,
          h * 32, qf, mk, MEM_LEN, &ps[w][c15][0], c15, g8, g, lsum, oa0, oa1);
  lsum += __shfl_xor(lsum, 16, 64);
  lsum += __shfl_xor(lsum, 32, 64);
  const float inv = 1.0f / lsum;
  unsigned long long pk0 = 0, pk1 = 0;
#pragma unroll
  for (int r = 0; r < 4; ++r) {
    pk0 |= (unsigned long long)f2bf(oa0[r] * inv) << (16 * r);
    pk1 |= (unsigned long long)f2bf(oa1[r] * inv) << (16 * r);
  }
  unsigned short* adst = p.cabufrot + rot * 32768;
  ast((unsigned long long*)(adst + h * 4096 + arow * 32 + g * 4), pk0);
  ast((unsigned long long*)(adst + h * 4096 + arow * 32 + 16 + g * 4), pk1);
}

// ---------------------------------------------------------------------------
// Phase: 64x64 out-projection + residual + pst. WGs 0..7.
// ALAY 0: A = attn layout [8][128][32], K=256; ALAY 1: A = [128][1024], K=1024.
// RES 1: + fp32 res; RES 2: + LN(Yp,pstp,gp,bp).
// ---------------------------------------------------------------------------
template <int ALAY, int RES>
__device__ void ph_oproj(const MegaP& p, int wg,
    const unsigned short* __restrict__ ab,
    const unsigned short* __restrict__ W, const float* __restrict__ bias,
    const float* __restrict__ res,
    const float* __restrict__ Yp, const float* __restrict__ pstp,
    const float* __restrict__ gp, const float* __restrict__ bp,
    float* __restrict__ Yo, float* __restrict__ psto)
{
  if (wg >= 8) return;
  const int tid = threadIdx.x, l = tid & 63, w = tid >> 6;
  const int c15 = l & 15, g8 = (l >> 4) * 8, r0v = (l >> 4) * 4;
  const int rowb = (wg >> 2) * 64 + w * 16;
  const int arow = rowb + c15;
  const int cb = wg & 3, colb = cb * 64;
  constexpr int K = ALAY ? 1024 : 256;

  f32x4 acc[4] = {};
  const unsigned short* wp = W + (colb + c15) * K + g8;
  for (int kc = 0; kc < K / 32; ++kc) {
    short8 af;
    if (ALAY == 0) af = *(const short8*)(ab + kc * 4096 + arow * 32 + g8);
    else           af = *(const short8*)(ab + arow * 1024 + kc * 32 + g8);
#pragma unroll
    for (int t = 0; t < 4; ++t)
      acc[t] = MFMA(af, *(const short8*)(wp + t * 16 * K + kc * 32), acc[t]);
  }

  float mp[4], rp[4];
  if (RES == 2) {
#pragma unroll
    for (int r = 0; r < 4; ++r) ln_stats(pstp, rowb + r0v + r, mp[r], rp[r]);
  }
  float v[4][4];
#pragma unroll
  for (int t = 0; t < 4; ++t) {
    const int col = colb + t * 16 + c15;
    const float bb = bias[col];
    float gpp = 0.f, bpp = 0.f;
    if (RES == 2) { gpp = gp[col]; bpp = bp[col]; }
#pragma unroll
    for (int r = 0; r < 4; ++r) {
      const int row = rowb + r0v + r;
      float x = acc[t][r] + bb;
      if (RES == 1) x += res[row * 256 + col];
      if (RES == 2) x += (Yp[row * 256 + col] - mp[r]) * rp[r] * gpp + bpp;
      ast(&Yo[row * 256 + col], x);
      v[t][r] = x;
    }
  }
#pragma unroll
  for (int r = 0; r < 4; ++r) {
    float s  = v[0][r] + v[1][r] + v[2][r] + v[3][r];
    float ss = v[0][r]*v[0][r] + v[1][r]*v[1][r] + v[2][r]*v[2][r] + v[3][r]*v[3][r];
#pragma unroll
    for (int m = 1; m < 16; m <<= 1) {
      s  += __shfl_xor(s, m, 64);
      ss += __shfl_xor(ss, m, 64);
    }
    if (c15 == 0) {
      const int row = rowb + r0v + r;
      ast(&psto[row * 8 + cb * 2], s);
      ast(&psto[row * 8 + cb * 2 + 1], ss);
    }
  }
}

// ---------------------------------------------------------------------------
// Phase: FF1 (LN2(Y2) @ W1 + relu -> midrot). WGs 0..31 (2 rb x 16 cb of 64).
// ---------------------------------------------------------------------------
__device__ void ph_ff1(const MegaP& p, int wg, int s, int li) {
  const int rb = wg >> 4, cb = wg & 15;
  const int tid = threadIdx.x, l = tid & 63, w = tid >> 6;
  const int c15 = l & 15, g8 = (l >> 4) * 8, r0v = (l >> 4) * 4;
  const int rowb = rb * 64 + w * 16;
  const int arow = rowb + c15;
  const int colb = cb * 64;
  const int rot = s * 2 + li;

  const float* Ya = p.Y2rot + rot * 32768;
  const float* lga = p.ln2_g + li * 256;
  const float* lba = p.ln2_b + li * 256;
  float mean, rstd;
  ln_stats(p.pst2rot + rot * 1024, arow, mean, rstd);

  const unsigned short* W1 = p.ffW1b + li * 262144;
  const float* b1 = p.ff_b1 + li * 1024;
  f32x4 acc[4] = {};
  const unsigned short* wp = W1 + (colb + c15) * 256 + g8;
  for (int kc = 0; kc < 8; ++kc) {
    short8 af = afragLN(Ya + arow * 256, lga, lba, kc * 32 + g8, mean, rstd);
#pragma unroll
    for (int t = 0; t < 4; ++t)
      acc[t] = MFMA(af, *(const short8*)(wp + t * 16 * 256 + kc * 32), acc[t]);
  }
  unsigned short* mid = p.midrot + rot * 131072;
#pragma unroll
  for (int t = 0; t < 4; ++t) {
    const int col = colb + t * 16 + c15;
    const float bb = b1[col];
#pragma unroll
    for (int r = 0; r < 4; ++r)
      ast(&mid[(rowb + r0v + r) * 1024 + col], f2bf(fmaxf(acc[t][r] + bb, 0.f)));
  }
}

// ---------------------------------------------------------------------------
// THE mega kernel: persistent, 32 WGs, col-partitioned weight-stationary.
// ---------------------------------------------------------------------------
__global__ __launch_bounds__(256, 1) void mega_k(MegaP p) {
  __shared__ float sscene[64][2];
  __shared__ unsigned short sq[4][16][32];
  __shared__ unsigned short ps[4][16][96];
  const int wg = blockIdx.x;
  unsigned tgt = 0;
#define GB gridbar(p.barCnt, tgt)

  for (int s = 0; s < PRED; ++s) {
    ph_embed(p, wg, s, sscene);
    GB;
    for (int li = 0; li < 2; ++li) {
      const int rot = s * 2 + li;
      ph_qkv(p, wg, s, li);
      GB;
      ph_attn_sa(p, ps, wg, s, li);
      GB;
      if (li == 0)
        ph_oproj<0, 1>(p, wg, p.abufrot + rot * 32768,
                       p.dxdb + 3 * 131072, p.sa_bo,
                       p.x0rot + s * 32768, nullptr, nullptr, nullptr, nullptr,
                       p.Y1rot + rot * 32768, p.pst1rot + rot * 1024);
      else
        ph_oproj<0, 2>(p, wg, p.abufrot + rot * 32768,
                       p.dxdb + 3 * 131072 + 65536, p.sa_bo + 256,
                       nullptr, p.Y3rot + (rot - 1) * 32768,
                       p.pst3rot + (rot - 1) * 1024, p.ln3_g, p.ln3_b,
                       p.Y1rot + rot * 32768, p.pst1rot + rot * 1024);
      GB;
      ph_attn_ca(p, sq, ps, wg, s, li);
      GB;
      ph_oproj<0, 2>(p, wg, p.cabufrot + rot * 32768,
                     p.dxdb + 7 * 131072 + li * 65536, p.ca_bo + li * 256,
                     nullptr, p.Y1rot + rot * 32768, p.pst1rot + rot * 1024,
                     p.ln1_g + li * 256, p.ln1_b + li * 256,
                     p.Y2rot + rot * 32768, p.pst2rot + rot * 1024);
      GB;
      ph_ff1(p, wg, s, li);
      GB;
      ph_oproj<1, 2>(p, wg, p.midrot + rot * 131072,
                     p.ffW2b + li * 262144, p.ff_b2 + li * 256,
                     nullptr, p.Y2rot + rot * 32768, p.pst2rot + rot * 1024,
                     p.ln2_g + li * 256, p.ln2_b + li * 256,
                     p.Y3rot + rot * 32768, p.pst3rot + rot * 1024);
      GB;
    }
  }
  ph_embed(p, wg, PRED, sscene);   // final out-projection
#undef GB
}

// ---------------------------------------------------------------------------
// Prologue kernels
// ---------------------------------------------------------------------------
__global__ void cvt8_k(const float* p0, const float* p1, const float* p2,
                       const float* p3, const float* p4, const float* p5,
                       const float* p6, const float* p7, unsigned short* dst)
{
  const float* s;
  switch (blockIdx.z) {
    case 0: s = p0; break; case 1: s = p1; break;
    case 2: s = p2; break; case 3: s = p3; break;
    case 4: s = p4; break; case 5: s = p5; break;
    case 6: s = p6; break; default: s = p7; break;
  }
  int i = blockIdx.x * 256 + threadIdx.x;
  dst[blockIdx.z * 131072 + i] = f2bf(s[i]);
}

__global__ void cvtff_k(const float* w1, const float* w2, unsigned short* dst)
{
  const float* s = blockIdx.z ? w2 : w1;
  int i = blockIdx.x * 256 + threadIdx.x;
  dst[blockIdx.z * 524288 + i] = f2bf(s[i]);
}

__global__ void cvtinw_k(const float* w, unsigned short* dst)
{
  int i = blockIdx.x * 256 + threadIdx.x;
  if (i >= 256 * 160) return;
  int n = i / 160, k = i - n * 160;
  dst[i] = (k < 130) ? f2bf(w[n * 130 + k]) : (unsigned short)0;
}

__global__ void pe_k(float* peA, float* peT)
{
  int i = blockIdx.x * 256 + threadIdx.x;
  if (i < 128 * 256) {
    int row = i >> 8, c = i & 255, pp = c >> 1;
    float dv = expf((float)(2 * pp) * (-9.210340371976184f / 256.f));
    float ang = (float)row * dv;
    peA[i] = (c & 1) ? cosf(ang) : sinf(ang);
  } else if (i < 140 * 256) {
    int j = i - 32768;
    int s = j >> 8, c = j & 255, pp = c >> 1;
    float dv = expf((float)(2 * pp) * (-9.210340371976184f / 256.f));
    float ang = (float)s * dv;
    peT[j] = (c & 1) ? cosf(ang) : sinf(ang);
  }
}

// memory K/V precompute; V blocked [kb][256][16]. Grid (16, 8, 2).
__global__ __launch_bounds__(256) void memkv_k(
    const float* __restrict__ mem, const unsigned short* __restrict__ dxd,
    const float* __restrict__ bk, const float* __restrict__ bvv,
    unsigned short* __restrict__ memK, unsigned short* __restrict__ memV)
{
  const int li = blockIdx.z;
  const int y = blockIdx.y;
  const bool isK = y < 4;
  const int colb = (y & 3) * 64;
  const unsigned short* W = dxd + (isK ? 5 : 6) * 131072 + li * 65536;
  const float* bias = (isK ? bk : bvv) + li * 256;
  unsigned short* Ko = memK + li * 262144;
  unsigned short* Vo = memV + li * 262144;
  const int tid = threadIdx.x, l = tid & 63, w = tid >> 6;
  const int c15 = l & 15, g8 = (l >> 4) * 8, r0v = (l >> 4) * 4;
  const int rowb = blockIdx.x * 64 + w * 16;
  const int arow = rowb + c15;
  f32x4 acc[4] = {};
  const unsigned short* wp = W + (colb + c15) * 256 + g8;
  for (int kc = 0; kc < 8; ++kc) {
    short8 af = afrag8(mem + arow * 256 + kc * 32 + g8);
#pragma unroll
    for (int t = 0; t < 4; ++t)
      acc[t] = MFMA(af, *(const short8*)(wp + t * 16 * 256 + kc * 32), acc[t]);
  }
  const int kb = blockIdx.x * 4 + w;
#pragma unroll
  for (int t = 0; t < 4; ++t) {
    const int col = colb + t * 16 + c15;
    const float bb = bias[col];
    if (isK) {
      const int hh = col >> 5, d = col & 31;
#pragma unroll
      for (int r = 0; r < 4; ++r)
        Ko[hh * (MEM_LEN * 32) + (rowb + r0v + r) * 32 + d] = f2bf(acc[t][r] + bb);
    } else {
      unsigned long long pk = 0;
#pragma unroll
      for (int r = 0; r < 4; ++r)
        pk |= (unsigned long long)f2bf(acc[t][r] + bb) << (16 * r);
      *(unsigned long long*)&Vo[(kb * 256 + col) * 16 + r0v] = pk;
    }
  }
}

__global__ void initbar_k(unsigned* b) { b[0] = 0; }

// ---------------------------------------------------------------------------
extern "C" void kernel_launch(void* const* d_in, const int* in_sizes, int n_in,
                              void* d_out, int out_size, void* d_ws, size_t ws_size,
                              hipStream_t stream)
{
  // workspace layout (~30 MB)
  float* ws = (float*)d_ws;
  float* peA = ws;                            // 32768
  float* peT = peA + 32768;                   // 3072
  float* x0rot = peT + 3072;                  // 12*32768
  float* Y1rot = x0rot + 393216;              // 24*32768
  float* Y2rot = Y1rot + 786432;
  float* Y3rot = Y2rot + 786432;
  float* pst1rot = Y3rot + 786432;            // 24*1024
  float* pst2rot = pst1rot + 24576;
  float* pst3rot = pst2rot + 24576;
  unsigned short* xb0rot = (unsigned short*)(pst3rot + 24576);  // 12*32768
  unsigned short* qrot = xb0rot + 393216;     // 24*32768
  unsigned short* abufrot = qrot + 786432;
  unsigned short* cabufrot = abufrot + 786432;
  unsigned short* midrot = cabufrot + 786432; // 24*131072
  unsigned short* saK = midrot + 3145728;     // 2*393216
  unsigned short* saV = saK + 786432;
  unsigned short* memK = saV + 786432;        // 2*262144
  unsigned short* memV = memK + 524288;
  unsigned short* dxdb = memV + 524288;       // 8*131072
  unsigned short* ffW1b = dxdb + 1048576;     // 524288
  unsigned short* ffW2b = ffW1b + 524288;
  unsigned short* inWb = ffW2b + 524288;      // 40960
  unsigned* bar = (unsigned*)(inWb + 40960);

  const dim3 blk(256);

  cvt8_k<<<dim3(512, 1, 8), blk, 0, stream>>>(
      (const float*)d_in[8], (const float*)d_in[10], (const float*)d_in[12],
      (const float*)d_in[14], (const float*)d_in[16], (const float*)d_in[18],
      (const float*)d_in[20], (const float*)d_in[22], dxdb);
  cvtff_k<<<dim3(2048, 1, 2), blk, 0, stream>>>((const float*)d_in[24],
                                                (const float*)d_in[26], ffW1b);
  cvtinw_k<<<160, blk, 0, stream>>>((const float*)d_in[4], inWb);
  pe_k<<<140, blk, 0, stream>>>(peA, peT);
  memkv_k<<<dim3(16, 8, 2), blk, 0, stream>>>((const float*)d_in[2], dxdb,
      (const float*)d_in[19], (const float*)d_in[21], memK, memV);
  initbar_k<<<1, 1, 0, stream>>>(bar);

  MegaP p;
  p.last_pos = (const float*)d_in[0];
  p.ds = (const float*)d_in[1];
  p.mask = (const float*)d_in[3];
  p.in_b = (const float*)d_in[5];
  p.out_W = (const float*)d_in[6];
  p.out_b = (const float*)d_in[7];
  p.sa_bq = (const float*)d_in[9];  p.sa_bk = (const float*)d_in[11];
  p.sa_bv = (const float*)d_in[13]; p.sa_bo = (const float*)d_in[15];
  p.ca_bq = (const float*)d_in[17]; p.ca_bo = (const float*)d_in[23];
  p.ff_b1 = (const float*)d_in[25]; p.ff_b2 = (const float*)d_in[27];
  p.ln1_g = (const float*)d_in[28]; p.ln1_b = (const float*)d_in[29];
  p.ln2_g = (const float*)d_in[30]; p.ln2_b = (const float*)d_in[31];
  p.ln3_g = (const float*)d_in[32]; p.ln3_b = (const float*)d_in[33];
  p.out = (float*)d_out;
  p.peA = peA; p.peT = peT;
  p.x0rot = x0rot; p.xb0rot = xb0rot;
  p.qrot = qrot; p.abufrot = abufrot; p.cabufrot = cabufrot;
  p.Y1rot = Y1rot; p.Y2rot = Y2rot; p.Y3rot = Y3rot;
  p.pst1rot = pst1rot; p.pst2rot = pst2rot; p.pst3rot = pst3rot;
  p.midrot = midrot;
  p.saK = saK; p.saV = saV; p.memK = memK; p.memV = memV;
  p.dxdb = dxdb; p.ffW1b = ffW1b; p.ffW2b = ffW2b; p.inWb = inWb;
  p.barCnt = bar;

  mega_k<<<dim3(NWG), blk, 0, stream>>>(p);
}

// Round 13
// 2659.270 us; speedup vs baseline: 1.3499x; 1.2539x over previous
//
#include <hip/hip_runtime.h>
#include <math.h>

#define AGENTS 128
#define DIM 256
#define NHEADS 8
#define MEM_LEN 1024
#define MLP_DIM 1024
#define PRED 12
#define MAXS (PRED * AGENTS)   // 1536

typedef __attribute__((ext_vector_type(8))) short short8;
typedef __attribute__((ext_vector_type(4))) float f32x4;

#define MFMA(a, b, c) __builtin_amdgcn_mfma_f32_16x16x32_bf16(a, b, c, 0, 0, 0)

__device__ __forceinline__ unsigned short f2bf(float f) {
  union { float f; unsigned u; } v; v.f = f;
  unsigned r = v.u + 0x7fffu + ((v.u >> 16) & 1u);   // RNE
  return (unsigned short)(r >> 16);
}
__device__ __forceinline__ float bfval(unsigned short b) {
  union { unsigned u; float f; } v; v.u = (unsigned)b << 16; return v.f;
}
__device__ __forceinline__ short8 afrag8(const float* p) {
  float4 a = *(const float4*)p;
  float4 b = *(const float4*)(p + 4);
  short8 r;
  r[0] = (short)f2bf(a.x); r[1] = (short)f2bf(a.y);
  r[2] = (short)f2bf(a.z); r[3] = (short)f2bf(a.w);
  r[4] = (short)f2bf(b.x); r[5] = (short)f2bf(b.y);
  r[6] = (short)f2bf(b.z); r[7] = (short)f2bf(b.w);
  return r;
}

// LN stats from 4 col-block partials pst[row][cb]=(sum,sumsq)
__device__ __forceinline__ void ln_stats(const float* __restrict__ pst, int row,
                                         float& mean, float& rstd) {
  float4 p0 = *(const float4*)(pst + row * 8);
  float4 p1 = *(const float4*)(pst + row * 8 + 4);
  float s  = p0.x + p0.z + p1.x + p1.z;
  float ss = p0.y + p0.w + p1.y + p1.w;
  mean = s * (1.0f / 256.0f);
  rstd = rsqrtf(ss * (1.0f / 256.0f) - mean * mean + 1e-5f);
}

__device__ __forceinline__ short8 afragLN(const float* __restrict__ yr,
                                          const float* __restrict__ lg,
                                          const float* __restrict__ lb,
                                          int k, float mean, float rstd) {
  float4 a = *(const float4*)(yr + k), b = *(const float4*)(yr + k + 4);
  float4 ga = *(const float4*)(lg + k), gb = *(const float4*)(lg + k + 4);
  float4 ba = *(const float4*)(lb + k), bb = *(const float4*)(lb + k + 4);
  short8 r;
  r[0] = (short)f2bf((a.x - mean) * rstd * ga.x + ba.x);
  r[1] = (short)f2bf((a.y - mean) * rstd * ga.y + ba.y);
  r[2] = (short)f2bf((a.z - mean) * rstd * ga.z + ba.z);
  r[3] = (short)f2bf((a.w - mean) * rstd * ga.w + ba.w);
  r[4] = (short)f2bf((b.x - mean) * rstd * gb.x + bb.x);
  r[5] = (short)f2bf((b.y - mean) * rstd * gb.y + bb.y);
  r[6] = (short)f2bf((b.z - mean) * rstd * gb.z + bb.z);
  r[7] = (short)f2bf((b.w - mean) * rstd * gb.w + bb.w);
  return r;
}

// one 16-key score tile: MFMA -> exp -> bf16 pack + lsum
__device__ __forceinline__ void score_tile(short8 kf, short8 qf, const float* m4,
                                           unsigned short* dst, float& lsum) {
  const float scale = 0.17677669529663687f;
  f32x4 zz = {};
  f32x4 sc = MFMA(kf, qf, zz);
  unsigned short b0 = f2bf(__expf(sc[0] * scale + m4[0]));
  unsigned short b1 = f2bf(__expf(sc[1] * scale + m4[1]));
  unsigned short b2 = f2bf(__expf(sc[2] * scale + m4[2]));
  unsigned short b3 = f2bf(__expf(sc[3] * scale + m4[3]));
  lsum += bfval(b0) + bfval(b1) + bfval(b2) + bfval(b3);
  uint2 u2;
  u2.x = (unsigned)b0 | ((unsigned)b1 << 16);
  u2.y = (unsigned)b2 | ((unsigned)b3 << 16);
  *(uint2*)dst = u2;
}

// ---------------------------------------------------------------------------
// Fused embed: prev-step out-proj + scene update + embed GEMM. Grid (2,4).
// s==PRED: out-proj only (grid (2,1)).
// ---------------------------------------------------------------------------
__global__ __launch_bounds__(256) void embed2_k(
    const float* __restrict__ last_pos, const float* __restrict__ ds,
    const unsigned short* __restrict__ inWb, const float* __restrict__ inb,
    const float* __restrict__ peA, const float* __restrict__ peT,
    const float* __restrict__ Y3, const float* __restrict__ pst3,
    const float* __restrict__ g3, const float* __restrict__ b3,
    const float* __restrict__ outW, const float* __restrict__ outB,
    float* __restrict__ out, float* __restrict__ sceneArr,
    float* __restrict__ x0, unsigned short* __restrict__ xb0, int s)
{
  __shared__ float sscene[64][2];
  const int rb = blockIdx.x, cb = blockIdx.y;
  const int tid = threadIdx.x;
  if (tid < 128) {
    const int lrow = tid >> 1, j = tid & 1;
    const int row = rb * 64 + lrow;
    float sv;
    if (s > 0) {
      float mean, rstd; ln_stats(pst3, row, mean, rstd);
      const float* yr = Y3 + row * 256;
      const float* wr = outW + j * 256;
      float a = 0.f;
      for (int k = 0; k < 256; k += 4) {
        float4 y = *(const float4*)(yr + k);
        float4 gg = *(const float4*)(g3 + k);
        float4 bb = *(const float4*)(b3 + k);
        float4 ww = *(const float4*)(wr + k);
        a += ((y.x - mean) * rstd * gg.x + bb.x) * ww.x
           + ((y.y - mean) * rstd * gg.y + bb.y) * ww.y
           + ((y.z - mean) * rstd * gg.z + bb.z) * ww.z
           + ((y.w - mean) * rstd * gg.w + bb.w) * ww.w;
      }
      a += outB[j];
      if (cb == 0) out[((s - 1) * AGENTS + row) * 2 + j] = a;
      sv = sceneArr[(s - 1) * 256 + row * 2 + j] + a;
    } else {
      sv = last_pos[row * 2 + j];
    }
    if (s < PRED) {
      sceneArr[s * 256 + row * 2 + j] = sv;   // identical dup across cb: benign
      sscene[lrow][j] = sv;
    }
  }
  __syncthreads();
  if (s == PRED) return;

  const int l = tid & 63, w = tid >> 6;
  const int c15 = l & 15, g8 = (l >> 4) * 8, r0v = (l >> 4) * 4;
  const int rowb = rb * 64 + w * 16;
  const int arow = rowb + c15;
  const int lsrow = w * 16 + c15;
  const int colb = cb * 64;
  f32x4 acc[4] = {};
  const unsigned short* wp = inWb + (colb + c15) * 160 + g8;
  for (int kc = 0; kc < 5; ++kc) {
    short8 af;
#pragma unroll
    for (int j = 0; j < 8; ++j) {
      int kk = kc * 32 + g8 + j;
      float v = (kk < 2) ? sscene[lsrow][kk]
                         : ((kk < 130) ? ds[arow * 128 + (kk - 2)] : 0.f);
      af[j] = (short)f2bf(v);
    }
#pragma unroll
    for (int t = 0; t < 4; ++t)
      acc[t] = MFMA(af, *(const short8*)(wp + t * 16 * 160 + kc * 32), acc[t]);
  }
#pragma unroll
  for (int t = 0; t < 4; ++t) {
    const int col = colb + t * 16 + c15;
    const float bb = inb[col] + peT[s * DIM + col];
#pragma unroll
    for (int r = 0; r < 4; ++r) {
      const int row = rowb + r0v + r;
      float v = acc[t][r] + bb + peA[row * DIM + col];
      x0[row * DIM + col] = v;
      xb0[row * DIM + col] = f2bf(v);
    }
  }
}

// ---------------------------------------------------------------------------
// Fused SA: QKV projections (own head) + flash attention. Grid (2, 8).
// AMODE 0: A = xb0 bf16; AMODE 1: A = LN(Y3, pst3). Current-step K/V kept in
// LDS (own-half written to cache for future steps); older keys from cache.
// ---------------------------------------------------------------------------
template <int AMODE>
__global__ __launch_bounds__(256) void attnsa_k(
    const unsigned short* __restrict__ ab,
    const float* __restrict__ Ya, const float* __restrict__ psta,
    const float* __restrict__ lga, const float* __restrict__ lba,
    const unsigned short* __restrict__ Wq, const float* __restrict__ bq,
    const unsigned short* __restrict__ Wk, const float* __restrict__ bk,
    const unsigned short* __restrict__ Wv, const float* __restrict__ bv,
    unsigned short* __restrict__ Ko, unsigned short* __restrict__ Vo,
    const float* __restrict__ mask, unsigned short* __restrict__ Ob, int s)
{
  __shared__ unsigned short klds[128][32];   // current 128 keys, own head
  __shared__ unsigned short vlds[32][128];   // dim-major
  __shared__ unsigned short sq[4][16][32];
  __shared__ unsigned short ps[4][16][96];
  const int rb = blockIdx.x, h = blockIdx.y;
  const int tid = threadIdx.x, l = tid & 63, w = tid >> 6;
  const int c15 = l & 15, g = l >> 4, g8 = g * 8, r0v = g * 4;

  // ---- K/V projection: all 128 current rows, cols h*32..h*32+32 ----
#pragma unroll
  for (int ti = 0; ti < 2; ++ti) {
    const int arow = w * 32 + ti * 16 + c15;
    float mean = 0.f, rstd = 0.f;
    if (AMODE == 1) ln_stats(psta, arow, mean, rstd);
    short8 af[8];
#pragma unroll
    for (int kc = 0; kc < 8; ++kc)
      af[kc] = (AMODE == 0) ? *(const short8*)(ab + arow * 256 + kc * 32 + g8)
                            : afragLN(Ya + arow * 256, lga, lba, kc * 32 + g8,
                                      mean, rstd);
#pragma unroll
    for (int ct = 0; ct < 2; ++ct) {
      const int col = h * 32 + ct * 16 + c15;
      const int lc = ct * 16 + c15;
      f32x4 acck = {}, accv = {};
      const unsigned short* wpk = Wk + col * 256 + g8;
      const unsigned short* wpv = Wv + col * 256 + g8;
#pragma unroll
      for (int kc = 0; kc < 8; ++kc) {
        acck = MFMA(af[kc], *(const short8*)(wpk + kc * 32), acck);
        accv = MFMA(af[kc], *(const short8*)(wpv + kc * 32), accv);
      }
      const float bbk = bk[col], bbv = bv[col];
#pragma unroll
      for (int r = 0; r < 4; ++r) {
        const int row = w * 32 + ti * 16 + r0v + r;
        unsigned short kvv = f2bf(acck[r] + bbk);
        unsigned short vvv = f2bf(accv[r] + bbv);
        klds[row][lc] = kvv;
        vlds[lc][row] = vvv;
        if ((row >> 6) == rb) {   // own half -> cache (single writer)
          Ko[h * (MAXS * 32) + (s * 128 + row) * 32 + lc] = kvv;
          Vo[col * MAXS + s * 128 + row] = vvv;
        }
      }
    }
  }

  // ---- Q projection: own 64 rows ----
  {
    const int arow = rb * 64 + w * 16 + c15;
    float mean = 0.f, rstd = 0.f;
    if (AMODE == 1) ln_stats(psta, arow, mean, rstd);
    f32x4 q0 = {}, q1 = {};
    const unsigned short* wp0 = Wq + (h * 32 + c15) * 256 + g8;
    const unsigned short* wp1 = Wq + (h * 32 + 16 + c15) * 256 + g8;
    for (int kc = 0; kc < 8; ++kc) {
      short8 af = (AMODE == 0) ? *(const short8*)(ab + arow * 256 + kc * 32 + g8)
                               : afragLN(Ya + arow * 256, lga, lba,
                                         kc * 32 + g8, mean, rstd);
      q0 = MFMA(af, *(const short8*)(wp0 + kc * 32), q0);
      q1 = MFMA(af, *(const short8*)(wp1 + kc * 32), q1);
    }
    const float b0 = bq[h * 32 + c15], b1 = bq[h * 32 + 16 + c15];
#pragma unroll
    for (int r = 0; r < 4; ++r) {
      sq[w][r0v + r][c15]      = f2bf(q0[r] + b0);
      sq[w][r0v + r][16 + c15] = f2bf(q1[r] + b1);
    }
  }
  __syncthreads();
  short8 qf = *(const short8*)&sq[w][c15][g8];

  const int qrow = rb * 64 + w * 16 + c15;
  float mk[2][4][4];
#pragma unroll
  for (int pp = 0; pp < 2; ++pp)
#pragma unroll
    for (int t = 0; t < 4; ++t)
#pragma unroll
      for (int r = 0; r < 4; ++r)
        mk[pp][t][r] = mask[qrow * AGENTS + pp * 64 + t * 16 + g * 4 + r];

  const unsigned short* kh = Ko + h * (MAXS * 32);
  const unsigned short* vh = Vo + h * 32 * MAXS;
  const int S = (s + 1) * 128, fb = S - 128;
  f32x4 oa0 = {}, oa1 = {};
  float lsum = 0.f;
  unsigned short* psrow = &ps[w][c15][0];

  for (int kc = 0; kc < S; kc += 64) {
    const int pp = (kc >> 6) & 1;
    const bool fresh = kc >= fb;
#pragma unroll
    for (int t = 0; t < 4; ++t) {
      const int key = kc + t * 16 + c15;
      short8 kf = fresh ? *(const short8*)&klds[key - fb][g8]
                        : *(const short8*)(kh + key * 32 + g8);
      score_tile(kf, qf, mk[pp][t], psrow + t * 16 + g * 4, lsum);
    }
#pragma unroll
    for (int ks = 0; ks < 2; ++ks) {
      short8 pf = *(const short8*)(psrow + ks * 32 + g8);
      const int j = kc + ks * 32 + g8;
      short8 v0 = fresh ? *(const short8*)&vlds[c15][j - fb]
                        : *(const short8*)(vh + c15 * MAXS + j);
      short8 v1 = fresh ? *(const short8*)&vlds[16 + c15][j - fb]
                        : *(const short8*)(vh + (16 + c15) * MAXS + j);
      oa0 = MFMA(v0, pf, oa0);
      oa1 = MFMA(v1, pf, oa1);
    }
  }
  lsum += __shfl_xor(lsum, 16, 64);
  lsum += __shfl_xor(lsum, 32, 64);
  const float inv = 1.0f / lsum;
#pragma unroll
  for (int r = 0; r < 4; ++r) {
    Ob[qrow * DIM + h * 32 + g * 4 + r]      = f2bf(oa0[r] * inv);
    Ob[qrow * DIM + h * 32 + 16 + g * 4 + r] = f2bf(oa1[r] * inv);
  }
}

// ---------------------------------------------------------------------------
// CA attention with fused Q-projection (from LN1(Y1,pst1)). Grid (2, 8).
// ---------------------------------------------------------------------------
__global__ __launch_bounds__(256) void attnca_k(
    const float* __restrict__ Ya, const float* __restrict__ psta,
    const float* __restrict__ lga, const float* __restrict__ lba,
    const unsigned short* __restrict__ Wq, const float* __restrict__ bq,
    const unsigned short* __restrict__ Kc, const unsigned short* __restrict__ Vt,
    const float* __restrict__ mask, unsigned short* __restrict__ Ob)
{
  __shared__ unsigned short sq[4][16][32];
  __shared__ unsigned short ps[4][16][96];
  const int rb = blockIdx.x, h = blockIdx.y;
  const int tid = threadIdx.x, l = tid & 63, w = tid >> 6;
  const int c15 = l & 15, g = l >> 4, g8 = g * 8, r0v = g * 4;
  const int arow = rb * 64 + w * 16 + c15;

  float mean, rstd;
  ln_stats(psta, arow, mean, rstd);
  f32x4 q0 = {}, q1 = {};
  const unsigned short* wp = Wq + (h * 32 + c15) * 256 + g8;
  for (int kc = 0; kc < 8; ++kc) {
    short8 af = afragLN(Ya + arow * 256, lga, lba, kc * 32 + g8, mean, rstd);
    q0 = MFMA(af, *(const short8*)(wp + kc * 32), q0);
    q1 = MFMA(af, *(const short8*)(wp + 16 * 256 + kc * 32), q1);
  }
  {
    const float b0 = bq[h * 32 + c15], b1 = bq[h * 32 + 16 + c15];
#pragma unroll
    for (int r = 0; r < 4; ++r) {
      sq[w][r0v + r][c15]      = f2bf(q0[r] + b0);
      sq[w][r0v + r][16 + c15] = f2bf(q1[r] + b1);
    }
  }
  short8 qf = *(const short8*)&sq[w][c15][g8];   // wave-private

  float mk[2][4][4];
#pragma unroll
  for (int pp = 0; pp < 2; ++pp)
#pragma unroll
    for (int t = 0; t < 4; ++t)
#pragma unroll
      for (int r = 0; r < 4; ++r)
        mk[pp][t][r] = mask[arow * AGENTS + pp * 64 + t * 16 + g * 4 + r];

  const unsigned short* kh = Kc + h * MEM_LEN * 32;
  const unsigned short* vh = Vt + h * 32 * MEM_LEN;
  unsigned short* psrow = &ps[w][c15][0];
  f32x4 oa0 = {}, oa1 = {};
  float lsum = 0.f;

  for (int kc = 0; kc < MEM_LEN; kc += 64) {
    const int pp = (kc >> 6) & 1;
#pragma unroll
    for (int t = 0; t < 4; ++t) {
      short8 kf = *(const short8*)(kh + (kc + t * 16 + c15) * 32 + g8);
      score_tile(kf, qf, mk[pp][t], psrow + t * 16 + g * 4, lsum);
    }
#pragma unroll
    for (int ks = 0; ks < 2; ++ks) {
      short8 pf = *(const short8*)(psrow + ks * 32 + g8);
      const int j = kc + ks * 32 + g8;
      short8 v0 = *(const short8*)(vh + c15 * MEM_LEN + j);
      short8 v1 = *(const short8*)(vh + (16 + c15) * MEM_LEN + j);
      oa0 = MFMA(v0, pf, oa0);
      oa1 = MFMA(v1, pf, oa1);
    }
  }
  lsum += __shfl_xor(lsum, 16, 64);
  lsum += __shfl_xor(lsum, 32, 64);
  const float inv = 1.0f / lsum;
#pragma unroll
  for (int r = 0; r < 4; ++r) {
    Ob[arow * DIM + h * 32 + g * 4 + r]      = f2bf(oa0[r] * inv);
    Ob[arow * DIM + h * 32 + 16 + g * 4 + r] = f2bf(oa1[r] * inv);
  }
}

// ---------------------------------------------------------------------------
// Wide projection GEMM (R5-proven). Block = 64 rows x 64 cols, grid (2, N/64).
// AMODE: 0 bf16 A (ab, lda); 1 fp32 Y + LN. RES: 0 none; 1 fp32 resid;
// 2 LN(Yp,pstp,gp,bp). EPI: 0 Yo fp32 + pst; 1 relu->bf16 mido [*,1024].
// ---------------------------------------------------------------------------
template <int AMODE, int RES, int EPI>
__global__ __launch_bounds__(256) void wproj_k(
    const unsigned short* __restrict__ ab, int lda,
    const float* __restrict__ Ya, const float* __restrict__ psta,
    const float* __restrict__ lga, const float* __restrict__ lba,
    const unsigned short* __restrict__ W, const float* __restrict__ bias, int K,
    const float* __restrict__ res,
    const float* __restrict__ Yp, const float* __restrict__ pstp,
    const float* __restrict__ gp, const float* __restrict__ bp,
    float* __restrict__ Yo, float* __restrict__ psto,
    unsigned short* __restrict__ mido)
{
  const int tid = threadIdx.x, l = tid & 63, w = tid >> 6;
  const int c15 = l & 15, g8 = (l >> 4) * 8, r0v = (l >> 4) * 4;
  const int rowb = blockIdx.x * 64 + w * 16;
  const int arow = rowb + c15;
  const int cb = blockIdx.y;
  const int colb = cb * 64;

  float meanA = 0.f, rstdA = 0.f;
  if (AMODE == 1) ln_stats(psta, arow, meanA, rstdA);

  const int KC = K >> 5;
  f32x4 acc[4] = {};
  const unsigned short* wp = W + (colb + c15) * K + g8;
  for (int kc = 0; kc < KC; ++kc) {
    short8 af;
    if (AMODE == 0) af = *(const short8*)(ab + arow * lda + kc * 32 + g8);
    else af = afragLN(Ya + arow * 256, lga, lba, kc * 32 + g8, meanA, rstdA);
#pragma unroll
    for (int t = 0; t < 4; ++t)
      acc[t] = MFMA(af, *(const short8*)(wp + t * 16 * K + kc * 32), acc[t]);
  }

  float mp[4], rp[4];
  if (RES == 2) {
#pragma unroll
    for (int r = 0; r < 4; ++r) ln_stats(pstp, rowb + r0v + r, mp[r], rp[r]);
  }

  float v[4][4];
#pragma unroll
  for (int t = 0; t < 4; ++t) {
    const int col = colb + t * 16 + c15;
    const float bb = bias[col];
    float gpp = 0.f, bpp = 0.f;
    if (RES == 2) { gpp = gp[col]; bpp = bp[col]; }
#pragma unroll
    for (int r = 0; r < 4; ++r) {
      const int row = rowb + r0v + r;
      float x = acc[t][r] + bb;
      if (RES == 1) x += res[row * 256 + col];
      if (RES == 2) x += (Yp[row * 256 + col] - mp[r]) * rp[r] * gpp + bpp;
      if (EPI == 0) Yo[row * 256 + col] = x;
      if (EPI == 1) mido[row * 1024 + col] = f2bf(fmaxf(x, 0.f));
      v[t][r] = x;
    }
  }
  if (EPI == 0) {
#pragma unroll
    for (int r = 0; r < 4; ++r) {
      float s  = v[0][r] + v[1][r] + v[2][r] + v[3][r];
      float ss = v[0][r]*v[0][r] + v[1][r]*v[1][r] + v[2][r]*v[2][r] + v[3][r]*v[3][r];
#pragma unroll
      for (int m = 1; m < 16; m <<= 1) {
        s  += __shfl_xor(s, m, 64);
        ss += __shfl_xor(ss, m, 64);
      }
      if (c15 == 0) {
        const int row = rowb + r0v + r;
        psto[row * 8 + cb * 2]     = s;
        psto[row * 8 + cb * 2 + 1] = ss;
      }
    }
  }
}

// ---------------------------------------------------------------------------
// memory K/V precompute (prologue). Grid (16, 8): y<4 -> K cols, y>=4 -> V.
// ---------------------------------------------------------------------------
__global__ __launch_bounds__(256) void memkv_k(
    const float* __restrict__ mem,
    const unsigned short* __restrict__ Wk, const float* __restrict__ bk,
    const unsigned short* __restrict__ Wv, const float* __restrict__ bv,
    unsigned short* __restrict__ Ko, unsigned short* __restrict__ Vo)
{
  const int tid = threadIdx.x, l = tid & 63, w = tid >> 6;
  const int c15 = l & 15, g8 = (l >> 4) * 8, r0v = (l >> 4) * 4;
  const int rowb = blockIdx.x * 64 + w * 16;
  const int arow = rowb + c15;
  const int y = blockIdx.y;
  const bool isK = y < 4;
  const int colb = (y & 3) * 64;
  const unsigned short* W = isK ? Wk : Wv;
  const float* bias = isK ? bk : bv;

  f32x4 acc[4] = {};
  const unsigned short* wp = W + (colb + c15) * 256 + g8;
  for (int kc = 0; kc < 8; ++kc) {
    short8 af = afrag8(mem + arow * 256 + kc * 32 + g8);
#pragma unroll
    for (int t = 0; t < 4; ++t)
      acc[t] = MFMA(af, *(const short8*)(wp + t * 16 * 256 + kc * 32), acc[t]);
  }
#pragma unroll
  for (int t = 0; t < 4; ++t) {
    const int col = colb + t * 16 + c15;
    const float bb = bias[col];
    const int hh = col >> 5, d = col & 31;
#pragma unroll
    for (int r = 0; r < 4; ++r) {
      const int row = rowb + r0v + r;
      unsigned short val = f2bf(acc[t][r] + bb);
      if (isK) Ko[hh * MEM_LEN * 32 + row * 32 + d] = val;
      else     Vo[col * MEM_LEN + row] = val;
    }
  }
}

// ---------------------------------------------------------------------------
// Prologue converters / tables
// ---------------------------------------------------------------------------
__global__ void cvt8_k(const float* p0, const float* p1, const float* p2,
                       const float* p3, const float* p4, const float* p5,
                       const float* p6, const float* p7, unsigned short* dst)
{
  const float* s;
  switch (blockIdx.z) {
    case 0: s = p0; break; case 1: s = p1; break;
    case 2: s = p2; break; case 3: s = p3; break;
    case 4: s = p4; break; case 5: s = p5; break;
    case 6: s = p6; break; default: s = p7; break;
  }
  int i = blockIdx.x * 256 + threadIdx.x;
  dst[blockIdx.z * 131072 + i] = f2bf(s[i]);
}

__global__ void cvtff_k(const float* w1, const float* w2, unsigned short* dst)
{
  const float* s = blockIdx.z ? w2 : w1;
  int i = blockIdx.x * 256 + threadIdx.x;
  dst[blockIdx.z * 524288 + i] = f2bf(s[i]);
}

__global__ void cvtinw_k(const float* w, unsigned short* dst)
{
  int i = blockIdx.x * 256 + threadIdx.x;
  if (i >= 256 * 160) return;
  int n = i / 160, k = i - n * 160;
  dst[i] = (k < 130) ? f2bf(w[n * 130 + k]) : (unsigned short)0;
}

__global__ void pe_k(float* peA, float* peT)
{
  int i = blockIdx.x * 256 + threadIdx.x;
  if (i < 128 * 256) {
    int row = i >> 8, c = i & 255, p = c >> 1;
    float dv = expf((float)(2 * p) * (-9.210340371976184f / 256.f));
    float ang = (float)row * dv;
    peA[i] = (c & 1) ? cosf(ang) : sinf(ang);
  } else if (i < 140 * 256) {
    int j = i - 32768;
    int s = j >> 8, c = j & 255, p = c >> 1;
    float dv = expf((float)(2 * p) * (-9.210340371976184f / 256.f));
    float ang = (float)s * dv;
    peT[j] = (c & 1) ? cosf(ang) : sinf(ang);
  }
}

// ---------------------------------------------------------------------------
extern "C" void kernel_launch(void* const* d_in, const int* in_sizes, int n_in,
                              void* d_out, int out_size, void* d_ws, size_t ws_size,
                              hipStream_t stream)
{
  const float* last_pos      = (const float*)d_in[0];
  const float* decoder_state = (const float*)d_in[1];
  const float* memory        = (const float*)d_in[2];
  const float* agent_mask    = (const float*)d_in[3];
  const float* in_W  = (const float*)d_in[4];
  const float* in_b  = (const float*)d_in[5];
  const float* out_W = (const float*)d_in[6];
  const float* out_b = (const float*)d_in[7];
  const float* sa_bq = (const float*)d_in[9];
  const float* sa_bk = (const float*)d_in[11];
  const float* sa_bv = (const float*)d_in[13];
  const float* sa_bo = (const float*)d_in[15];
  const float* ca_bq = (const float*)d_in[17];
  const float* ca_bk = (const float*)d_in[19];
  const float* ca_bv = (const float*)d_in[21];
  const float* ca_bo = (const float*)d_in[23];
  const float* ff_b1 = (const float*)d_in[25];
  const float* ff_b2 = (const float*)d_in[27];
  const float* ln1_g = (const float*)d_in[28];
  const float* ln1_b = (const float*)d_in[29];
  const float* ln2_g = (const float*)d_in[30];
  const float* ln2_b = (const float*)d_in[31];
  const float* ln3_g = (const float*)d_in[32];
  const float* ln3_b = (const float*)d_in[33];
  float* out = (float*)d_out;

  // fp32 workspace
  float* ws       = (float*)d_ws;
  float* sceneArr = ws;                  // 13*256
  float* x0       = sceneArr + 13 * 256; // 32768
  float* Y1       = x0 + 32768;
  float* Y2       = Y1 + 32768;
  float* Y3       = Y2 + 32768;
  float* pst1     = Y3 + 32768;          // 1024
  float* pst2     = pst1 + 1024;
  float* pst3     = pst2 + 1024;
  float* peA      = pst3 + 1024;         // 32768
  float* peT      = peA + 32768;         // 3072
  // bf16 region
  unsigned short* xb0   = (unsigned short*)(peT + 3072);  // 32768
  unsigned short* abuf  = xb0 + 32768;                    // 32768
  unsigned short* mid   = abuf + 32768;                   // 131072
  unsigned short* saK   = mid + 131072;                   // 2 x [8][1536][32]
  unsigned short* saV   = saK + 2 * MAXS * 256;           // 2 x [256][1536]
  unsigned short* memK  = saV + 2 * MAXS * 256;           // 2 x [8][1024][32]
  unsigned short* memV  = memK + 2 * MEM_LEN * 256;       // 2 x [256][1024]
  unsigned short* dxdb  = memV + 2 * MEM_LEN * 256;       // 8 x [2][256][256]
  unsigned short* ffW1b = dxdb + 8 * 131072;
  unsigned short* ffW2b = ffW1b + 524288;
  unsigned short* inWb  = ffW2b + 524288;

  const dim3 blk(256);

  // ---- prologue ----
  cvt8_k<<<dim3(512, 1, 8), blk, 0, stream>>>(
      (const float*)d_in[8], (const float*)d_in[10], (const float*)d_in[12],
      (const float*)d_in[14], (const float*)d_in[16], (const float*)d_in[18],
      (const float*)d_in[20], (const float*)d_in[22], dxdb);
  cvtff_k<<<dim3(2048, 1, 2), blk, 0, stream>>>((const float*)d_in[24],
                                                (const float*)d_in[26], ffW1b);
  cvtinw_k<<<160, blk, 0, stream>>>(in_W, inWb);
  pe_k<<<140, blk, 0, stream>>>(peA, peT);
  for (int l = 0; l < 2; ++l) {
    memkv_k<<<dim3(16, 8), blk, 0, stream>>>(
        memory,
        dxdb + 5 * 131072 + l * 65536, ca_bk + l * 256,
        dxdb + 6 * 131072 + l * 65536, ca_bv + l * 256,
        memK + l * MEM_LEN * 256, memV + l * MEM_LEN * 256);
  }

  // ---- AR steps ----
  for (int s = 0; s < PRED; ++s) {
    embed2_k<<<dim3(2, 4), blk, 0, stream>>>(
        last_pos, decoder_state, inWb, in_b, peA, peT,
        Y3, pst3, ln3_g + 256, ln3_b + 256, out_W, out_b,
        out, sceneArr, x0, xb0, s);

    for (int l = 0; l < 2; ++l) {
      const unsigned short* saWq = dxdb + 0 * 131072 + l * 65536;
      const unsigned short* saWk = dxdb + 1 * 131072 + l * 65536;
      const unsigned short* saWv = dxdb + 2 * 131072 + l * 65536;
      const unsigned short* saWo = dxdb + 3 * 131072 + l * 65536;
      const unsigned short* caWq = dxdb + 4 * 131072 + l * 65536;
      const unsigned short* caWo = dxdb + 7 * 131072 + l * 65536;
      unsigned short* saKl = saK + l * MAXS * 256;
      unsigned short* saVl = saV + l * MAXS * 256;

      if (l == 0) {
        attnsa_k<0><<<dim3(2, 8), blk, 0, stream>>>(
            xb0, nullptr, nullptr, nullptr, nullptr,
            saWq, sa_bq, saWk, sa_bk, saWv, sa_bv,
            saKl, saVl, agent_mask, abuf, s);
        wproj_k<0, 1, 0><<<dim3(2, 4), blk, 0, stream>>>(
            abuf, 256, nullptr, nullptr, nullptr, nullptr,
            saWo, sa_bo, 256, x0, nullptr, nullptr, nullptr, nullptr,
            Y1, pst1, nullptr);
      } else {
        attnsa_k<1><<<dim3(2, 8), blk, 0, stream>>>(
            nullptr, Y3, pst3, ln3_g, ln3_b,
            saWq, sa_bq + 256, saWk, sa_bk + 256, saWv, sa_bv + 256,
            saKl, saVl, agent_mask, abuf, s);
        wproj_k<0, 2, 0><<<dim3(2, 4), blk, 0, stream>>>(
            abuf, 256, nullptr, nullptr, nullptr, nullptr,
            saWo, sa_bo + 256, 256, nullptr, Y3, pst3, ln3_g, ln3_b,
            Y1, pst1, nullptr);
      }
      attnca_k<<<dim3(2, 8), blk, 0, stream>>>(
          Y1, pst1, ln1_g + l * 256, ln1_b + l * 256,
          caWq, ca_bq + l * 256,
          memK + l * MEM_LEN * 256, memV + l * MEM_LEN * 256,
          agent_mask, abuf);
      wproj_k<0, 2, 0><<<dim3(2, 4), blk, 0, stream>>>(
          abuf, 256, nullptr, nullptr, nullptr, nullptr,
          caWo, ca_bo + l * 256, 256, nullptr, Y1, pst1,
          ln1_g + l * 256, ln1_b + l * 256,
          Y2, pst2, nullptr);
      wproj_k<1, 0, 1><<<dim3(2, 16), blk, 0, stream>>>(
          nullptr, 0, Y2, pst2, ln2_g + l * 256, ln2_b + l * 256,
          ffW1b + l * 262144, ff_b1 + l * 1024, 256,
          nullptr, nullptr, nullptr, nullptr, nullptr,
          nullptr, nullptr, mid);
      wproj_k<0, 2, 0><<<dim3(2, 4), blk, 0, stream>>>(
          mid, 1024, nullptr, nullptr, nullptr, nullptr,
          ffW2b + l * 262144, ff_b2 + l * 256, 1024,
          nullptr, Y2, pst2, ln2_g + l * 256, ln2_b + l * 256,
          Y3, pst3, nullptr);
    }
  }
  // final out-projection (s == PRED path)
  embed2_k<<<dim3(2, 1), blk, 0, stream>>>(
      last_pos, decoder_state, inWb, in_b, peA, peT,
      Y3, pst3, ln3_g + 256, ln3_b + 256, out_W, out_b,
      out, sceneArr, x0, xb0, PRED);
}